// Round 2
// baseline (621.525 us; speedup 1.0000x reference)
//
#include <hip/hip_runtime.h>

// HGT encoder, MI355X — ROUND 10.
// R9 analysis: GEMMs dominated by B-staging (scalar f2bf + LDS transpose,
// MfmaUtil 4.7%, 7.7M bank conflicts) and per-tile fp32->bf16 A conversion.
// Changes:
//  1. One-time bf16 pre-transposed weights: WqT/WeffT/WoutT (BT[n][k]).
//  2. bf16 mirror Xbf of X (copy_init + out-GEMM epilogue) -> A loads are
//     native short8, half the bytes, zero VALU convert. Bit-identical math.
//  3. GEMMs read B fragments directly from global (L2-hot): no LDS, no
//     syncthreads, no bank conflicts. N=128 tile per block (8 n-frags).
//  4. CSR count/scatter fused 8 launches -> 2.
// MFMA layouts (guide-verified): A[m=lane&15][k=quad*8+j],
// B[k=quad*8+j][n=lane&15], D[row=quad*4+reg][col=lane&15].

#define NTOT  80000
#define ETOT  600000
#define NSRC  120000

typedef unsigned short u16;
typedef unsigned int   u32;
typedef __attribute__((ext_vector_type(8))) short short8;
typedef __attribute__((ext_vector_type(4))) float f32x4;

__device__ __forceinline__ float bf2f(u16 u){
  union { u32 i; float f; } v; v.i = ((u32)u) << 16; return v.f;
}
__device__ __forceinline__ u16 f2bf(float f){
  union { float f; u32 i; } v; v.f = f;
  u32 x = v.i;
  return (u16)((x + 0x7fffu + ((x >> 16) & 1u)) >> 16);   // RNE
}
__device__ __forceinline__ void unp4(uint4 a, float* o){
  union { u32 i; float f; } t;
  t.i = a.x << 16;        o[0]=t.f;  t.i = a.x & 0xffff0000u; o[1]=t.f;
  t.i = a.y << 16;        o[2]=t.f;  t.i = a.y & 0xffff0000u; o[3]=t.f;
  t.i = a.z << 16;        o[4]=t.f;  t.i = a.z & 0xffff0000u; o[5]=t.f;
  t.i = a.w << 16;        o[6]=t.f;  t.i = a.w & 0xffff0000u; o[7]=t.f;
}
__device__ __forceinline__ void load16bf(const u16* p, float* o){
  unp4(*(const uint4*)p, o); unp4(*(const uint4*)(p + 8), o + 8);
}

// ---------------- init: X fp32 + Xbf bf16 mirror ----------------

__global__ __launch_bounds__(256) void copy_init(
    const float* __restrict__ xg, const float* __restrict__ xd,
    const float* __restrict__ xr, float* __restrict__ X, u16* __restrict__ Xbf)
{
  int i = blockIdx.x * 256 + threadIdx.x;        // float4 units; 2,560,000 total
  if (i >= 2560000) return;
  const float* src; int off;
  if (i < 1600000)      { src = xg; off = i; }
  else if (i < 2240000) { src = xd; off = i - 1600000; }
  else                  { src = xr; off = i - 2240000; }
  float4 v = ((const float4*)src)[off];
  ((float4*)X)[i] = v;
  uint2 b;
  b.x = (u32)f2bf(v.x) | ((u32)f2bf(v.y) << 16);
  b.y = (u32)f2bf(v.z) | ((u32)f2bf(v.w) << 16);
  ((uint2*)Xbf)[i] = b;
}

__global__ __launch_bounds__(256) void zero_cc(int* __restrict__ cnt, int* __restrict__ cur){
  int i = blockIdx.x * 256 + threadIdx.x;
  if (i < NTOT){ cnt[i] = 0; cur[i] = 0; }
}

// ---------------- CSR build (fused over the 4 relations) ----------------

__global__ __launch_bounds__(256) void count_all(
    const int* __restrict__ e0, const int* __restrict__ e1,
    const int* __restrict__ e2, const int* __restrict__ e3,
    int* __restrict__ cnt)
{
  int e = blockIdx.x * 256 + threadIdx.x;
  if (e >= ETOT) return;
  const int* ei; int E, loc, offd;
  if (e < 300000)      { ei = e0; E = 300000; loc = e;          offd = 0; }
  else if (e < 450000) { ei = e1; E = 150000; loc = e - 300000; offd = 50000; }
  else if (e < 550000) { ei = e2; E = 100000; loc = e - 450000; offd = 0; }
  else                 { ei = e3; E = 50000;  loc = e - 550000; offd = 50000; }
  atomicAdd(&cnt[offd + ei[E + loc]], 1);
}

__global__ __launch_bounds__(256) void scan_partial(const int* __restrict__ cnt,
                             int* __restrict__ rowp, int* __restrict__ bsum){
  __shared__ int s[256];
  int tid = threadIdx.x;
  int i = blockIdx.x * 256 + tid;
  int v = (i < NTOT) ? cnt[i] : 0;
  s[tid] = v; __syncthreads();
  for (int off = 1; off < 256; off <<= 1){
    int t = (tid >= off) ? s[tid - off] : 0;
    __syncthreads();
    s[tid] += t;
    __syncthreads();
  }
  if (i < NTOT) rowp[i] = s[tid] - v;
  if (tid == 255) bsum[blockIdx.x] = s[255];
}

__global__ __launch_bounds__(256) void scan_block(int* __restrict__ bsum, int nb){
  __shared__ int b[512];
  __shared__ int p[256];
  int tid = threadIdx.x;
  b[tid]       = (tid < nb)       ? bsum[tid]       : 0;
  b[tid + 256] = (tid + 256 < nb) ? bsum[tid + 256] : 0;
  __syncthreads();
  int pv = b[2*tid] + b[2*tid + 1];
  p[tid] = pv; __syncthreads();
  for (int off = 1; off < 256; off <<= 1){
    int t = (tid >= off) ? p[tid - off] : 0;
    __syncthreads();
    p[tid] += t;
    __syncthreads();
  }
  int excl = p[tid] - pv;
  int e0 = excl, e1 = excl + b[2*tid];
  __syncthreads();
  if (2*tid < nb)   bsum[2*tid]     = e0;
  if (2*tid+1 < nb) bsum[2*tid + 1] = e1;
}

__global__ __launch_bounds__(256) void scan_add(int* __restrict__ rowp, const int* __restrict__ bsum){
  int i = blockIdx.x * 256 + threadIdx.x;
  if (i < NTOT) rowp[i] += bsum[i >> 8];
}

__global__ __launch_bounds__(256) void scatter_all(
    const int* __restrict__ e0, const int* __restrict__ e1,
    const int* __restrict__ e2, const int* __restrict__ e3,
    const int* __restrict__ rowp, int* __restrict__ cur,
    int* __restrict__ elist)
{
  int e = blockIdx.x * 256 + threadIdx.x;
  if (e >= ETOT) return;
  const int* ei; int E, loc, offd, rnoff, rel;
  if (e < 300000)      { ei = e0; E = 300000; loc = e;          offd = 0;     rnoff = 0;      rel = 0; }
  else if (e < 450000) { ei = e1; E = 150000; loc = e - 300000; offd = 50000; rnoff = 50000;  rel = 1; }
  else if (e < 550000) { ei = e2; E = 100000; loc = e - 450000; offd = 0;     rnoff = 100000; rel = 2; }
  else                 { ei = e3; E = 50000;  loc = e - 550000; offd = 50000; rnoff = 110000; rel = 3; }
  int src = ei[loc], dst = ei[E + loc];
  int dstg = offd + dst;
  int pos = atomicAdd(&cur[dstg], 1);
  elist[rowp[dstg] + pos] = ((rnoff + src) << 2) | rel;
}

// ---------------- fold Ak/Av into K/V weights (fp32, exact) ----------------

__global__ __launch_bounds__(256) void build_weff(
    const float* __restrict__ Wkqv, const float* __restrict__ Ak,
    const float* __restrict__ Av, float* __restrict__ Weff)
{
  int lr = blockIdx.y;
  int l = lr >> 2, r = lr & 3;
  int st = (r >= 2) ? 2 : 0;
  int elem = blockIdx.x * 256 + threadIdx.x;     // f*256 + j
  int f = elem >> 8, j = elem & 255;
  const float* W = Wkqv + (size_t)(l*3 + st) * 49152;
  float acc = 0.f;
  if (j < 128){
    int h = j >> 4, e = j & 15;
    const float* Am = Ak + (size_t)(l*4 + r) * 2048 + h*256;
#pragma unroll
    for (int d = 0; d < 16; d++) acc += W[f*384 + h*16 + d] * Am[d*16 + e];
  } else {
    int j2 = j - 128, h = j2 >> 4, e = j2 & 15;
    const float* Am = Av + (size_t)(l*4 + r) * 2048 + h*256;
#pragma unroll
    for (int d = 0; d < 16; d++) acc += W[f*384 + 256 + h*16 + d] * Am[d*16 + e];
  }
  Weff[(size_t)lr * 32768 + elem] = acc;
}

__global__ __launch_bounds__(256) void build_beff(
    const float* __restrict__ bkqv, const float* __restrict__ Ak,
    const float* __restrict__ Av, float* __restrict__ beff)
{
  int lr = blockIdx.x;
  int l = lr >> 2, r = lr & 3;
  int st = (r >= 2) ? 2 : 0;
  int j = threadIdx.x;
  const float* b = bkqv + (size_t)(l*3 + st) * 384;
  float acc = 0.f;
  if (j < 128){
    int h = j >> 4, e = j & 15;
    const float* Am = Ak + (size_t)(l*4 + r) * 2048 + h*256;
#pragma unroll
    for (int d = 0; d < 16; d++) acc += b[h*16 + d] * Am[d*16 + e];
  } else {
    int j2 = j - 128, h = j2 >> 4, e = j2 & 15;
    const float* Am = Av + (size_t)(l*4 + r) * 2048 + h*256;
#pragma unroll
    for (int d = 0; d < 16; d++) acc += b[256 + h*16 + d] * Am[d*16 + e];
  }
  beff[lr * 256 + j] = acc;
}

// ---------------- one-time weight transposes to bf16 BT[n][k] ----------------

// WqT[l3t][n*128+k] = bf16(Wkqv[(l3t)*49152 + k*384 + 128 + n]), 6*16384
__global__ __launch_bounds__(256) void conv_wq(const float* __restrict__ Wkqv, u16* __restrict__ WqT){
  int i = blockIdx.x * 256 + threadIdx.x;
  if (i >= 6*16384) return;
  int lt = i >> 14, rem = i & 16383, n = rem >> 7, k = rem & 127;
  WqT[i] = f2bf(Wkqv[(size_t)lt*49152 + k*384 + 128 + n]);
}

// WeffT[lr][n*128+k] = bf16(Weff[lr*32768 + k*256 + n]), 8*32768
__global__ __launch_bounds__(256) void conv_weff(const float* __restrict__ Weff, u16* __restrict__ WeffT){
  int i = blockIdx.x * 256 + threadIdx.x;
  if (i >= 8*32768) return;
  int lr = i >> 15, rem = i & 32767, n = rem >> 7, k = rem & 127;
  WeffT[i] = f2bf(Weff[(size_t)lr*32768 + k*256 + n]);
}

// WoutT[l3t][n*128+k] = bf16(Wout[lt*16384 + k*128 + n]), 6*16384
__global__ __launch_bounds__(256) void conv_wout(const float* __restrict__ Wout, u16* __restrict__ WoutT){
  int i = blockIdx.x * 256 + threadIdx.x;
  if (i >= 6*16384) return;
  int lt = i >> 14, rem = i & 16383, n = rem >> 7, k = rem & 127;
  WoutT[i] = f2bf(Wout[(size_t)lt*16384 + k*128 + n]);
}

// ---------------- MFMA GEMM core: C(bf16) = A(bf16 Mx128) @ BT^T + bias ----------------
// 64x128 tile / block, 4 waves x 16 rows, 8 n-frags. No LDS, B direct from L2.

__device__ __forceinline__ void gemm8_core(
    const u16* __restrict__ A, const u16* __restrict__ BT,
    int M, int bm, int bn, short8* af, f32x4* acc)
{
  int tid = threadIdx.x;
  int lane = tid & 63;
  int quad = lane >> 4, lm = lane & 15;
  int row = bm + (tid >> 6)*16 + lm;
  if (row < M){
    const u16* ap = A + (size_t)row*128 + quad*8;
#pragma unroll
    for (int c = 0; c < 4; c++) af[c] = *(const short8*)(ap + c*32);
  } else {
    short8 z = {0,0,0,0,0,0,0,0};
#pragma unroll
    for (int c = 0; c < 4; c++) af[c] = z;
  }
#pragma unroll
  for (int nt = 0; nt < 8; nt++) acc[nt] = (f32x4){0.f,0.f,0.f,0.f};
#pragma unroll
  for (int nt = 0; nt < 8; nt++){
    const u16* bp = BT + (size_t)(bn + nt*16 + lm)*128 + quad*8;
#pragma unroll
    for (int c = 0; c < 4; c++){
      short8 bf = *(const short8*)(bp + c*32);
      acc[nt] = __builtin_amdgcn_mfma_f32_16x16x32_bf16(af[c], bf, acc[nt], 0, 0, 0);
    }
  }
}

// Fused q-GEMM: all 3 node types, grid = 1252, N=128.
__global__ __launch_bounds__(256) void mfma_gemm_q(
    const u16* __restrict__ Xbf, const u16* __restrict__ WqTl,
    const float* __restrict__ bl, u16* __restrict__ qg)
{
  int by = blockIdx.x;
  int t, bm, M, roff;
  if (by < 782)       { t = 0; bm = by*64;          M = 50000; roff = 0; }
  else if (by < 1095) { t = 1; bm = (by-782)*64;    M = 20000; roff = 50000; }
  else                { t = 2; bm = (by-1095)*64;   M = 10000; roff = 70000; }
  const u16* A = Xbf + (size_t)roff*128;
  const u16* BT = WqTl + (size_t)t*16384;
  const float* bias = bl + (size_t)t*384 + 128;
  u16* C = qg + (size_t)roff*128;
  short8 af[4]; f32x4 acc[8];
  gemm8_core(A, BT, M, bm, 0, af, acc);
  int lane = threadIdx.x & 63, wave = threadIdx.x >> 6;
  int quad = lane >> 4, lm = lane & 15;
#pragma unroll
  for (int nt = 0; nt < 8; nt++){
    int col = nt*16 + lm;
    float bb = bias[col];
#pragma unroll
    for (int i = 0; i < 4; i++){
      int r = bm + wave*16 + quad*4 + i;
      if (r < M) C[(size_t)r*128 + col] = f2bf(acc[nt][i] + bb);
    }
  }
}

// Fused kv-GEMM: all 4 relations, grid = (2, 1878), N=256 in two 128 halves.
__global__ __launch_bounds__(256) void mfma_gemm_kv(
    const u16* __restrict__ Xbf, const u16* __restrict__ WeffTl,
    const float* __restrict__ beffl, u16* __restrict__ kv)
{
  int by = blockIdx.y;
  int r, bm, M, soff, ooff;
  if (by < 782)       { r = 0; bm = by*64;          M = 50000; soff = 0;     ooff = 0; }
  else if (by < 1564) { r = 1; bm = (by-782)*64;    M = 50000; soff = 0;     ooff = 50000; }
  else if (by < 1721) { r = 2; bm = (by-1564)*64;   M = 10000; soff = 70000; ooff = 100000; }
  else                { r = 3; bm = (by-1721)*64;   M = 10000; soff = 70000; ooff = 110000; }
  int bn = blockIdx.x * 128;
  const u16* A = Xbf + (size_t)soff*128;
  const u16* BT = WeffTl + (size_t)r*32768;
  const float* bias = beffl + (size_t)r*256;
  u16* C = kv + (size_t)ooff*256;
  short8 af[4]; f32x4 acc[8];
  gemm8_core(A, BT, M, bm, bn, af, acc);
  int lane = threadIdx.x & 63, wave = threadIdx.x >> 6;
  int quad = lane >> 4, lm = lane & 15;
#pragma unroll
  for (int nt = 0; nt < 8; nt++){
    int col = bn + nt*16 + lm;
    float bb = bias[col];
#pragma unroll
    for (int i = 0; i < 4; i++){
      int r2 = bm + wave*16 + quad*4 + i;
      if (r2 < M) C[(size_t)r2*256 + col] = f2bf(acc[nt][i] + bb);
    }
  }
}

// Fused out-GEMM: A = G(bf16), epilogue skip+relu+residual on X(fp32) + Xbf. grid = 1252.
__global__ __launch_bounds__(256) void mfma_gemm_out(
    const u16* __restrict__ Gall, const u16* __restrict__ WoutTl,
    const float* __restrict__ bl, const float* __restrict__ skipl,
    float* __restrict__ Xall, u16* __restrict__ Xbfall)
{
  int by = blockIdx.x;
  int t, bm, M, roff;
  if (by < 782)       { t = 0; bm = by*64;          M = 50000; roff = 0; }
  else if (by < 1095) { t = 1; bm = (by-782)*64;    M = 20000; roff = 50000; }
  else                { t = 2; bm = (by-1095)*64;   M = 10000; roff = 70000; }
  const u16* A = Gall + (size_t)roff*128;
  const u16* BT = WoutTl + (size_t)t*16384;
  const float* bias = bl + (size_t)t*128;
  float* X = Xall + (size_t)roff*128;
  u16* Xb = Xbfall + (size_t)roff*128;
  short8 af[4]; f32x4 acc[8];
  gemm8_core(A, BT, M, bm, 0, af, acc);
  float a_s = 1.f / (1.f + expf(-skipl[t]));
  float b_s = 1.f - a_s;
  int lane = threadIdx.x & 63, wave = threadIdx.x >> 6;
  int quad = lane >> 4, lm = lane & 15;
#pragma unroll
  for (int nt = 0; nt < 8; nt++){
    int col = nt*16 + lm;
    float bb = bias[col];
#pragma unroll
    for (int i = 0; i < 4; i++){
      int r = bm + wave*16 + quad*4 + i;
      if (r < M){
        float* xp = X + (size_t)r*128 + col;
        float x = *xp;
        float o = acc[nt][i] + bb;
        float xn = fmaxf(a_s*o + b_s*x, 0.f) + x;
        *xp = xn;
        Xb[(size_t)r*128 + col] = f2bf(xn);
      }
    }
  }
}

// ---------------- attention: one thread per (dst,head); 4-edge batched loads ----------------

__global__ __launch_bounds__(256) void attn_kernel(
    u16* __restrict__ qg,                   // NTOT x 128 bf16: q in, gelu(out) out
    const u16* __restrict__ kv,             // NSRC x 256 bf16: [k | v]
    const float* __restrict__ prel,         // + l*32
    const int* __restrict__ rowp, const int* __restrict__ cnt,
    const int* __restrict__ elist)
{
  int gid = blockIdx.x * 256 + threadIdx.x;
  int n = gid >> 3, h = gid & 7;
  if (n >= NTOT) return;
  float sc0 = prel[0*8+h]*0.25f, sc1 = prel[1*8+h]*0.25f,
        sc2 = prel[2*8+h]*0.25f, sc3 = prel[3*8+h]*0.25f;
  float q[16];
  load16bf(qg + (size_t)n * 128 + h*16, q);
  float acc[16] = {};
  float dsum = 0.f;
  int start = rowp[n], c = cnt[n];

  auto edge = [&](int ev, uint4 ka, uint4 kb, uint4 va, uint4 vb){
    float ke[16], ve[16];
    unp4(ka, ke); unp4(kb, ke + 8);
    unp4(va, ve); unp4(vb, ve + 8);
    float a = 0.f;
#pragma unroll
    for (int d = 0; d < 16; d++) a += q[d] * ke[d];
    int r = ev & 3;
    float s = (r == 0) ? sc0 : (r == 1) ? sc1 : (r == 2) ? sc2 : sc3;
    float ex = expf(a * s);
    dsum += ex;
#pragma unroll
    for (int d = 0; d < 16; d++) acc[d] += ex * ve[d];
  };

  int ii = 0;
#pragma unroll 1
  for (; ii + 4 <= c; ii += 4){
    int e0 = elist[start + ii + 0], e1 = elist[start + ii + 1],
        e2 = elist[start + ii + 2], e3 = elist[start + ii + 3];
    const u16* p0 = kv + (size_t)(e0 >> 2) * 256 + h*16;
    const u16* p1 = kv + (size_t)(e1 >> 2) * 256 + h*16;
    const u16* p2 = kv + (size_t)(e2 >> 2) * 256 + h*16;
    const u16* p3 = kv + (size_t)(e3 >> 2) * 256 + h*16;
    uint4 k0a = *(const uint4*)p0,         k0b = *(const uint4*)(p0 + 8);
    uint4 k1a = *(const uint4*)p1,         k1b = *(const uint4*)(p1 + 8);
    uint4 k2a = *(const uint4*)p2,         k2b = *(const uint4*)(p2 + 8);
    uint4 k3a = *(const uint4*)p3,         k3b = *(const uint4*)(p3 + 8);
    uint4 v0a = *(const uint4*)(p0 + 128), v0b = *(const uint4*)(p0 + 136);
    uint4 v1a = *(const uint4*)(p1 + 128), v1b = *(const uint4*)(p1 + 136);
    uint4 v2a = *(const uint4*)(p2 + 128), v2b = *(const uint4*)(p2 + 136);
    uint4 v3a = *(const uint4*)(p3 + 128), v3b = *(const uint4*)(p3 + 136);
    edge(e0, k0a, k0b, v0a, v0b);
    edge(e1, k1a, k1b, v1a, v1b);
    edge(e2, k2a, k2b, v2a, v2b);
    edge(e3, k3a, k3b, v3a, v3b);
  }
  for (; ii < c; ii++){
    int ev = elist[start + ii];
    const u16* p = kv + (size_t)(ev >> 2) * 256 + h*16;
    uint4 ka = *(const uint4*)p,         kb = *(const uint4*)(p + 8);
    uint4 va = *(const uint4*)(p + 128), vb = *(const uint4*)(p + 136);
    edge(ev, ka, kb, va, vb);
  }

  float inv = (c > 0) ? 1.f / dsum : 0.f;
  u16 o[16];
#pragma unroll
  for (int d = 0; d < 16; d++){
    float x = acc[d] * inv;
    o[d] = f2bf(0.5f * x * (1.f + erff(x * 0.70710678118654752f)));
  }
  uint4 p0, p1;
  p0.x = o[0]|(o[1]<<16);   p0.y = o[2]|(o[3]<<16);
  p0.z = o[4]|(o[5]<<16);   p0.w = o[6]|(o[7]<<16);
  p1.x = o[8]|(o[9]<<16);   p1.y = o[10]|(o[11]<<16);
  p1.z = o[12]|(o[13]<<16); p1.w = o[14]|(o[15]<<16);
  u16* op = qg + (size_t)n * 128 + h*16;
  *(uint4*)op = p0; *(uint4*)(op + 8) = p1;
}

// ---------------- host ----------------

extern "C" void kernel_launch(void* const* d_in, const int* in_sizes, int n_in,
                              void* d_out, int out_size, void* d_ws, size_t ws_size,
                              hipStream_t stream)
{
  const float* xg   = (const float*)d_in[0];
  const float* xd   = (const float*)d_in[1];
  const float* xr_  = (const float*)d_in[2];
  const float* Wkqv = (const float*)d_in[3];
  const float* bkqv = (const float*)d_in[4];
  const float* Ak   = (const float*)d_in[5];
  const float* Av   = (const float*)d_in[6];
  const float* prel = (const float*)d_in[7];
  const float* Wout = (const float*)d_in[8];
  const float* bout = (const float*)d_in[9];
  const float* skip = (const float*)d_in[10];
  const int* ei[4] = {(const int*)d_in[11], (const int*)d_in[12],
                      (const int*)d_in[13], (const int*)d_in[14]};

  float* X = (float*)d_out;

  char* p = (char*)d_ws;
  auto alloc = [&](size_t b)->void*{ void* r = (void*)p; p += (b + 255) & ~(size_t)255; return r; };
  int*   cnt   = (int*)  alloc((size_t)NTOT * 4);
  int*   rowp  = (int*)  alloc((size_t)NTOT * 4);
  int*   cur   = (int*)  alloc((size_t)NTOT * 4);
  int*   bsum  = (int*)  alloc(512 * 4);
  int*   elist = (int*)  alloc((size_t)ETOT * 4);
  float* Weff  = (float*)alloc((size_t)8 * 32768 * 4);
  float* beff  = (float*)alloc((size_t)8 * 256 * 4);
  u16*   qg    = (u16*)  alloc((size_t)NTOT * 128 * 2);    // 20.5 MB bf16
  u16*   kv    = (u16*)  alloc((size_t)NSRC * 256 * 2);    // 61.4 MB bf16
  u16*   Xbf   = (u16*)  alloc((size_t)NTOT * 128 * 2);    // 20.5 MB bf16
  u16*   WqT   = (u16*)  alloc((size_t)6 * 16384 * 2);
  u16*   WeffT = (u16*)  alloc((size_t)8 * 32768 * 2);
  u16*   WoutT = (u16*)  alloc((size_t)6 * 16384 * 2);
  (void)ws_size; (void)in_sizes; (void)n_in; (void)out_size;

  copy_init<<<10000, 256, 0, stream>>>(xg, xd, xr_, X, Xbf);
  zero_cc<<<313, 256, 0, stream>>>(cnt, cur);

  count_all<<<(ETOT+255)/256, 256, 0, stream>>>(ei[0], ei[1], ei[2], ei[3], cnt);
  scan_partial<<<313, 256, 0, stream>>>(cnt, rowp, bsum);
  scan_block<<<1, 256, 0, stream>>>(bsum, 313);
  scan_add<<<313, 256, 0, stream>>>(rowp, bsum);
  scatter_all<<<(ETOT+255)/256, 256, 0, stream>>>(ei[0], ei[1], ei[2], ei[3], rowp, cur, elist);

  build_weff<<<dim3(128, 8), 256, 0, stream>>>(Wkqv, Ak, Av, Weff);
  build_beff<<<8, 256, 0, stream>>>(bkqv, Ak, Av, beff);
  conv_wq<<<384, 256, 0, stream>>>(Wkqv, WqT);
  conv_weff<<<1024, 256, 0, stream>>>(Weff, WeffT);
  conv_wout<<<384, 256, 0, stream>>>(Wout, WoutT);

  for (int l = 0; l < 2; l++){
    mfma_gemm_q<<<1252, 256, 0, stream>>>(
        Xbf, WqT + (size_t)l*3*16384, bkqv + (size_t)l*3*384, qg);
    mfma_gemm_kv<<<dim3(2, 1878), 256, 0, stream>>>(
        Xbf, WeffT + (size_t)l*4*32768, beff + (size_t)l*4*256, kv);
    attn_kernel<<<2500, 256, 0, stream>>>(qg, kv, prel + l*32, rowp, cnt, elist);
    mfma_gemm_out<<<1252, 256, 0, stream>>>(
        qg, WoutT + (size_t)l*3*16384, bout + (size_t)l*3*128, skip + l*3, X, Xbf);
  }
}

// Round 3
// 470.052 us; speedup vs baseline: 1.3222x; 1.3222x over previous
//
#include <hip/hip_runtime.h>

// HGT encoder, MI355X — ROUND 11.
// R10 post-mortem: no-LDS GEMM was latency-bound (VGPR=52 -> compiler held
// ~2 B-frags in flight; serial L2-load->mfma chain; VALU 7.8%, Mfma 3.3%).
// R11: restore LDS for B but stage the PRE-CONVERTED bf16 BT tile (32KB)
// with 8 coalesced uint4 loads/thread (no f2bf, no transpose), XOR-swizzle
// ((byte>>8)&7)<<4 on write+read to kill the 16-way stride-256B conflict.
// Wave tile 32x128 (2 m-frags share each B-frag -> LDS traffic == MFMA time),
// block tile 128x128. VGPR ~140 -> 3 waves/SIMD for latency hiding.
// MFMA layouts (guide-verified): A[m=lane&15][k=quad*8+j],
// B[k=quad*8+j][n=lane&15], D[row=quad*4+reg][col=lane&15].

#define NTOT  80000
#define ETOT  600000
#define NSRC  120000

typedef unsigned short u16;
typedef unsigned int   u32;
typedef __attribute__((ext_vector_type(8))) short short8;
typedef __attribute__((ext_vector_type(4))) float f32x4;

__device__ __forceinline__ float bf2f(u16 u){
  union { u32 i; float f; } v; v.i = ((u32)u) << 16; return v.f;
}
__device__ __forceinline__ u16 f2bf(float f){
  union { float f; u32 i; } v; v.f = f;
  u32 x = v.i;
  return (u16)((x + 0x7fffu + ((x >> 16) & 1u)) >> 16);   // RNE
}
__device__ __forceinline__ void unp4(uint4 a, float* o){
  union { u32 i; float f; } t;
  t.i = a.x << 16;        o[0]=t.f;  t.i = a.x & 0xffff0000u; o[1]=t.f;
  t.i = a.y << 16;        o[2]=t.f;  t.i = a.y & 0xffff0000u; o[3]=t.f;
  t.i = a.z << 16;        o[4]=t.f;  t.i = a.z & 0xffff0000u; o[5]=t.f;
  t.i = a.w << 16;        o[6]=t.f;  t.i = a.w & 0xffff0000u; o[7]=t.f;
}
__device__ __forceinline__ void load16bf(const u16* p, float* o){
  unp4(*(const uint4*)p, o); unp4(*(const uint4*)(p + 8), o + 8);
}

// ---------------- init: X fp32 + Xbf bf16 mirror ----------------

__global__ __launch_bounds__(256) void copy_init(
    const float* __restrict__ xg, const float* __restrict__ xd,
    const float* __restrict__ xr, float* __restrict__ X, u16* __restrict__ Xbf)
{
  int i = blockIdx.x * 256 + threadIdx.x;        // float4 units; 2,560,000 total
  if (i >= 2560000) return;
  const float* src; int off;
  if (i < 1600000)      { src = xg; off = i; }
  else if (i < 2240000) { src = xd; off = i - 1600000; }
  else                  { src = xr; off = i - 2240000; }
  float4 v = ((const float4*)src)[off];
  ((float4*)X)[i] = v;
  uint2 b;
  b.x = (u32)f2bf(v.x) | ((u32)f2bf(v.y) << 16);
  b.y = (u32)f2bf(v.z) | ((u32)f2bf(v.w) << 16);
  ((uint2*)Xbf)[i] = b;
}

__global__ __launch_bounds__(256) void zero_cc(int* __restrict__ cnt, int* __restrict__ cur){
  int i = blockIdx.x * 256 + threadIdx.x;
  if (i < NTOT){ cnt[i] = 0; cur[i] = 0; }
}

// ---------------- CSR build (fused over the 4 relations) ----------------

__global__ __launch_bounds__(256) void count_all(
    const int* __restrict__ e0, const int* __restrict__ e1,
    const int* __restrict__ e2, const int* __restrict__ e3,
    int* __restrict__ cnt)
{
  int e = blockIdx.x * 256 + threadIdx.x;
  if (e >= ETOT) return;
  const int* ei; int E, loc, offd;
  if (e < 300000)      { ei = e0; E = 300000; loc = e;          offd = 0; }
  else if (e < 450000) { ei = e1; E = 150000; loc = e - 300000; offd = 50000; }
  else if (e < 550000) { ei = e2; E = 100000; loc = e - 450000; offd = 0; }
  else                 { ei = e3; E = 50000;  loc = e - 550000; offd = 50000; }
  atomicAdd(&cnt[offd + ei[E + loc]], 1);
}

__global__ __launch_bounds__(256) void scan_partial(const int* __restrict__ cnt,
                             int* __restrict__ rowp, int* __restrict__ bsum){
  __shared__ int s[256];
  int tid = threadIdx.x;
  int i = blockIdx.x * 256 + tid;
  int v = (i < NTOT) ? cnt[i] : 0;
  s[tid] = v; __syncthreads();
  for (int off = 1; off < 256; off <<= 1){
    int t = (tid >= off) ? s[tid - off] : 0;
    __syncthreads();
    s[tid] += t;
    __syncthreads();
  }
  if (i < NTOT) rowp[i] = s[tid] - v;
  if (tid == 255) bsum[blockIdx.x] = s[255];
}

__global__ __launch_bounds__(256) void scan_block(int* __restrict__ bsum, int nb){
  __shared__ int b[512];
  __shared__ int p[256];
  int tid = threadIdx.x;
  b[tid]       = (tid < nb)       ? bsum[tid]       : 0;
  b[tid + 256] = (tid + 256 < nb) ? bsum[tid + 256] : 0;
  __syncthreads();
  int pv = b[2*tid] + b[2*tid + 1];
  p[tid] = pv; __syncthreads();
  for (int off = 1; off < 256; off <<= 1){
    int t = (tid >= off) ? p[tid - off] : 0;
    __syncthreads();
    p[tid] += t;
    __syncthreads();
  }
  int excl = p[tid] - pv;
  int e0 = excl, e1 = excl + b[2*tid];
  __syncthreads();
  if (2*tid < nb)   bsum[2*tid]     = e0;
  if (2*tid+1 < nb) bsum[2*tid + 1] = e1;
}

__global__ __launch_bounds__(256) void scan_add(int* __restrict__ rowp, const int* __restrict__ bsum){
  int i = blockIdx.x * 256 + threadIdx.x;
  if (i < NTOT) rowp[i] += bsum[i >> 8];
}

__global__ __launch_bounds__(256) void scatter_all(
    const int* __restrict__ e0, const int* __restrict__ e1,
    const int* __restrict__ e2, const int* __restrict__ e3,
    const int* __restrict__ rowp, int* __restrict__ cur,
    int* __restrict__ elist)
{
  int e = blockIdx.x * 256 + threadIdx.x;
  if (e >= ETOT) return;
  const int* ei; int E, loc, offd, rnoff, rel;
  if (e < 300000)      { ei = e0; E = 300000; loc = e;          offd = 0;     rnoff = 0;      rel = 0; }
  else if (e < 450000) { ei = e1; E = 150000; loc = e - 300000; offd = 50000; rnoff = 50000;  rel = 1; }
  else if (e < 550000) { ei = e2; E = 100000; loc = e - 450000; offd = 0;     rnoff = 100000; rel = 2; }
  else                 { ei = e3; E = 50000;  loc = e - 550000; offd = 50000; rnoff = 110000; rel = 3; }
  int src = ei[loc], dst = ei[E + loc];
  int dstg = offd + dst;
  int pos = atomicAdd(&cur[dstg], 1);
  elist[rowp[dstg] + pos] = ((rnoff + src) << 2) | rel;
}

// ---------------- fold Ak/Av into K/V weights (fp32, exact) ----------------

__global__ __launch_bounds__(256) void build_weff(
    const float* __restrict__ Wkqv, const float* __restrict__ Ak,
    const float* __restrict__ Av, float* __restrict__ Weff)
{
  int lr = blockIdx.y;
  int l = lr >> 2, r = lr & 3;
  int st = (r >= 2) ? 2 : 0;
  int elem = blockIdx.x * 256 + threadIdx.x;     // f*256 + j
  int f = elem >> 8, j = elem & 255;
  const float* W = Wkqv + (size_t)(l*3 + st) * 49152;
  float acc = 0.f;
  if (j < 128){
    int h = j >> 4, e = j & 15;
    const float* Am = Ak + (size_t)(l*4 + r) * 2048 + h*256;
#pragma unroll
    for (int d = 0; d < 16; d++) acc += W[f*384 + h*16 + d] * Am[d*16 + e];
  } else {
    int j2 = j - 128, h = j2 >> 4, e = j2 & 15;
    const float* Am = Av + (size_t)(l*4 + r) * 2048 + h*256;
#pragma unroll
    for (int d = 0; d < 16; d++) acc += W[f*384 + 256 + h*16 + d] * Am[d*16 + e];
  }
  Weff[(size_t)lr * 32768 + elem] = acc;
}

__global__ __launch_bounds__(256) void build_beff(
    const float* __restrict__ bkqv, const float* __restrict__ Ak,
    const float* __restrict__ Av, float* __restrict__ beff)
{
  int lr = blockIdx.x;
  int l = lr >> 2, r = lr & 3;
  int st = (r >= 2) ? 2 : 0;
  int j = threadIdx.x;
  const float* b = bkqv + (size_t)(l*3 + st) * 384;
  float acc = 0.f;
  if (j < 128){
    int h = j >> 4, e = j & 15;
    const float* Am = Ak + (size_t)(l*4 + r) * 2048 + h*256;
#pragma unroll
    for (int d = 0; d < 16; d++) acc += b[h*16 + d] * Am[d*16 + e];
  } else {
    int j2 = j - 128, h = j2 >> 4, e = j2 & 15;
    const float* Am = Av + (size_t)(l*4 + r) * 2048 + h*256;
#pragma unroll
    for (int d = 0; d < 16; d++) acc += b[256 + h*16 + d] * Am[d*16 + e];
  }
  beff[lr * 256 + j] = acc;
}

// ---------------- one-time weight transposes to bf16 BT[n][k] ----------------

__global__ __launch_bounds__(256) void conv_wq(const float* __restrict__ Wkqv, u16* __restrict__ WqT){
  int i = blockIdx.x * 256 + threadIdx.x;
  if (i >= 6*16384) return;
  int lt = i >> 14, rem = i & 16383, n = rem >> 7, k = rem & 127;
  WqT[i] = f2bf(Wkqv[(size_t)lt*49152 + k*384 + 128 + n]);
}

__global__ __launch_bounds__(256) void conv_weff(const float* __restrict__ Weff, u16* __restrict__ WeffT){
  int i = blockIdx.x * 256 + threadIdx.x;
  if (i >= 8*32768) return;
  int lr = i >> 15, rem = i & 32767, n = rem >> 7, k = rem & 127;
  WeffT[i] = f2bf(Weff[(size_t)lr*32768 + k*256 + n]);
}

__global__ __launch_bounds__(256) void conv_wout(const float* __restrict__ Wout, u16* __restrict__ WoutT){
  int i = blockIdx.x * 256 + threadIdx.x;
  if (i >= 6*16384) return;
  int lt = i >> 14, rem = i & 16383, n = rem >> 7, k = rem & 127;
  WoutT[i] = f2bf(Wout[(size_t)lt*16384 + k*128 + n]);
}

// ---------------- MFMA GEMM: block tile 128x128, wave tile 32x128 ----------------
// BT tile (128 n-rows x 128 k, bf16 = 32KB) staged in LDS, XOR-swizzled.

__device__ __forceinline__ void stage_bt(const u16* __restrict__ src, u16* BTl){
  int tid = threadIdx.x;
  const uint4* g = (const uint4*)src;          // 2048 uint4 = 32KB
  uint4 tmp[8];
#pragma unroll
  for (int i = 0; i < 8; i++) tmp[i] = g[tid + i*256];
#pragma unroll
  for (int i = 0; i < 8; i++){
    int L = (tid + i*256) * 16;                // linear byte in tile
    int Ls = L ^ (((L >> 8) & 7) << 4);        // swizzle: row bits 8-10 -> bits 4-6
    *(uint4*)((char*)BTl + Ls) = tmp[i];
  }
  __syncthreads();
}

__device__ __forceinline__ void gemm_core(
    const u16* __restrict__ A, const u16* BTl, int M, int bm,
    f32x4 acc[8][2])
{
  int tid = threadIdx.x;
  int lane = tid & 63, w = tid >> 6;
  int quad = lane >> 4, lm = lane & 15;
  short8 af[2][4];
#pragma unroll
  for (int mf = 0; mf < 2; mf++){
    int row = bm + w*32 + mf*16 + lm;
    if (row < M){
      const u16* ap = A + (size_t)row*128 + quad*8;
#pragma unroll
      for (int c = 0; c < 4; c++) af[mf][c] = *(const short8*)(ap + c*32);
    } else {
      short8 z = {0,0,0,0,0,0,0,0};
#pragma unroll
      for (int c = 0; c < 4; c++) af[mf][c] = z;
    }
  }
#pragma unroll
  for (int nt = 0; nt < 8; nt++)
#pragma unroll
    for (int mf = 0; mf < 2; mf++) acc[nt][mf] = (f32x4){0.f,0.f,0.f,0.f};
#pragma unroll
  for (int nt = 0; nt < 8; nt++){
    int rowb = nt*16 + lm;
    int base = rowb*256 + quad*16;
    int sw = (rowb & 7) << 4;
#pragma unroll
    for (int c = 0; c < 4; c++){
      short8 bf = *(const short8*)((const char*)BTl + ((base + c*64) ^ sw));
      acc[nt][0] = __builtin_amdgcn_mfma_f32_16x16x32_bf16(af[0][c], bf, acc[nt][0], 0, 0, 0);
      acc[nt][1] = __builtin_amdgcn_mfma_f32_16x16x32_bf16(af[1][c], bf, acc[nt][1], 0, 0, 0);
    }
  }
}

// Fused q-GEMM: all 3 node types, grid = 627, tile 128 rows.
__global__ __launch_bounds__(256) void mfma_gemm_q(
    const u16* __restrict__ Xbf, const u16* __restrict__ WqTl,
    const float* __restrict__ bl, u16* __restrict__ qg)
{
  __shared__ u16 BTl[16384];
  int by = blockIdx.x;
  int t, bm, M, roff;
  if (by < 391)      { t = 0; bm = by*128;        M = 50000; roff = 0; }
  else if (by < 548) { t = 1; bm = (by-391)*128;  M = 20000; roff = 50000; }
  else               { t = 2; bm = (by-548)*128;  M = 10000; roff = 70000; }
  stage_bt(WqTl + (size_t)t*16384, BTl);
  const u16* A = Xbf + (size_t)roff*128;
  const float* bias = bl + (size_t)t*384 + 128;
  u16* C = qg + (size_t)roff*128;
  f32x4 acc[8][2];
  gemm_core(A, BTl, M, bm, acc);
  int lane = threadIdx.x & 63, w = threadIdx.x >> 6;
  int quad = lane >> 4, lm = lane & 15;
#pragma unroll
  for (int nt = 0; nt < 8; nt++){
    int col = nt*16 + lm;
    float bb = bias[col];
#pragma unroll
    for (int mf = 0; mf < 2; mf++)
#pragma unroll
      for (int i = 0; i < 4; i++){
        int r = bm + w*32 + mf*16 + quad*4 + i;
        if (r < M) C[(size_t)r*128 + col] = f2bf(acc[nt][mf][i] + bb);
      }
  }
}

// Fused kv-GEMM: all 4 relations, grid = (2, 940), tile 128 rows x 128 cols.
__global__ __launch_bounds__(256) void mfma_gemm_kv(
    const u16* __restrict__ Xbf, const u16* __restrict__ WeffTl,
    const float* __restrict__ beffl, u16* __restrict__ kv)
{
  __shared__ u16 BTl[16384];
  int by = blockIdx.y;
  int r, bm, M, soff, ooff;
  if (by < 391)      { r = 0; bm = by*128;        M = 50000; soff = 0;     ooff = 0; }
  else if (by < 782) { r = 1; bm = (by-391)*128;  M = 50000; soff = 0;     ooff = 50000; }
  else if (by < 861) { r = 2; bm = (by-782)*128;  M = 10000; soff = 70000; ooff = 100000; }
  else               { r = 3; bm = (by-861)*128;  M = 10000; soff = 70000; ooff = 110000; }
  int bn = blockIdx.x * 128;
  stage_bt(WeffTl + (size_t)r*32768 + (size_t)bn*128, BTl);
  const u16* A = Xbf + (size_t)soff*128;
  const float* bias = beffl + (size_t)r*256;
  u16* C = kv + (size_t)ooff*256;
  f32x4 acc[8][2];
  gemm_core(A, BTl, M, bm, acc);
  int lane = threadIdx.x & 63, w = threadIdx.x >> 6;
  int quad = lane >> 4, lm = lane & 15;
#pragma unroll
  for (int nt = 0; nt < 8; nt++){
    int col = bn + nt*16 + lm;
    float bb = bias[col];
#pragma unroll
    for (int mf = 0; mf < 2; mf++)
#pragma unroll
      for (int i = 0; i < 4; i++){
        int r2 = bm + w*32 + mf*16 + quad*4 + i;
        if (r2 < M) C[(size_t)r2*256 + col] = f2bf(acc[nt][mf][i] + bb);
      }
  }
}

// Fused out-GEMM: A = G(bf16), epilogue skip+relu+residual -> X(fp32) + Xbf. grid = 627.
__global__ __launch_bounds__(256) void mfma_gemm_out(
    const u16* __restrict__ Gall, const u16* __restrict__ WoutTl,
    const float* __restrict__ bl, const float* __restrict__ skipl,
    float* __restrict__ Xall, u16* __restrict__ Xbfall)
{
  __shared__ u16 BTl[16384];
  int by = blockIdx.x;
  int t, bm, M, roff;
  if (by < 391)      { t = 0; bm = by*128;        M = 50000; roff = 0; }
  else if (by < 548) { t = 1; bm = (by-391)*128;  M = 20000; roff = 50000; }
  else               { t = 2; bm = (by-548)*128;  M = 10000; roff = 70000; }
  stage_bt(WoutTl + (size_t)t*16384, BTl);
  const u16* A = Gall + (size_t)roff*128;
  const float* bias = bl + (size_t)t*128;
  float* X = Xall + (size_t)roff*128;
  u16* Xb = Xbfall + (size_t)roff*128;
  f32x4 acc[8][2];
  gemm_core(A, BTl, M, bm, acc);
  float a_s = 1.f / (1.f + expf(-skipl[t]));
  float b_s = 1.f - a_s;
  int lane = threadIdx.x & 63, w = threadIdx.x >> 6;
  int quad = lane >> 4, lm = lane & 15;
#pragma unroll
  for (int nt = 0; nt < 8; nt++){
    int col = nt*16 + lm;
    float bb = bias[col];
#pragma unroll
    for (int mf = 0; mf < 2; mf++)
#pragma unroll
      for (int i = 0; i < 4; i++){
        int r = bm + w*32 + mf*16 + quad*4 + i;
        if (r < M){
          float* xp = X + (size_t)r*128 + col;
          float x = *xp;
          float o = acc[nt][mf][i] + bb;
          float xn = fmaxf(a_s*o + b_s*x, 0.f) + x;
          *xp = xn;
          Xb[(size_t)r*128 + col] = f2bf(xn);
        }
      }
  }
}

// ---------------- attention: one thread per (dst,head); 4-edge batched loads ----------------

__global__ __launch_bounds__(256) void attn_kernel(
    u16* __restrict__ qg,                   // NTOT x 128 bf16: q in, gelu(out) out
    const u16* __restrict__ kv,             // NSRC x 256 bf16: [k | v]
    const float* __restrict__ prel,         // + l*32
    const int* __restrict__ rowp, const int* __restrict__ cnt,
    const int* __restrict__ elist)
{
  int gid = blockIdx.x * 256 + threadIdx.x;
  int n = gid >> 3, h = gid & 7;
  if (n >= NTOT) return;
  float sc0 = prel[0*8+h]*0.25f, sc1 = prel[1*8+h]*0.25f,
        sc2 = prel[2*8+h]*0.25f, sc3 = prel[3*8+h]*0.25f;
  float q[16];
  load16bf(qg + (size_t)n * 128 + h*16, q);
  float acc[16] = {};
  float dsum = 0.f;
  int start = rowp[n], c = cnt[n];

  auto edge = [&](int ev, uint4 ka, uint4 kb, uint4 va, uint4 vb){
    float ke[16], ve[16];
    unp4(ka, ke); unp4(kb, ke + 8);
    unp4(va, ve); unp4(vb, ve + 8);
    float a = 0.f;
#pragma unroll
    for (int d = 0; d < 16; d++) a += q[d] * ke[d];
    int r = ev & 3;
    float s = (r == 0) ? sc0 : (r == 1) ? sc1 : (r == 2) ? sc2 : sc3;
    float ex = expf(a * s);
    dsum += ex;
#pragma unroll
    for (int d = 0; d < 16; d++) acc[d] += ex * ve[d];
  };

  int ii = 0;
#pragma unroll 1
  for (; ii + 4 <= c; ii += 4){
    int e0 = elist[start + ii + 0], e1 = elist[start + ii + 1],
        e2 = elist[start + ii + 2], e3 = elist[start + ii + 3];
    const u16* p0 = kv + (size_t)(e0 >> 2) * 256 + h*16;
    const u16* p1 = kv + (size_t)(e1 >> 2) * 256 + h*16;
    const u16* p2 = kv + (size_t)(e2 >> 2) * 256 + h*16;
    const u16* p3 = kv + (size_t)(e3 >> 2) * 256 + h*16;
    uint4 k0a = *(const uint4*)p0,         k0b = *(const uint4*)(p0 + 8);
    uint4 k1a = *(const uint4*)p1,         k1b = *(const uint4*)(p1 + 8);
    uint4 k2a = *(const uint4*)p2,         k2b = *(const uint4*)(p2 + 8);
    uint4 k3a = *(const uint4*)p3,         k3b = *(const uint4*)(p3 + 8);
    uint4 v0a = *(const uint4*)(p0 + 128), v0b = *(const uint4*)(p0 + 136);
    uint4 v1a = *(const uint4*)(p1 + 128), v1b = *(const uint4*)(p1 + 136);
    uint4 v2a = *(const uint4*)(p2 + 128), v2b = *(const uint4*)(p2 + 136);
    uint4 v3a = *(const uint4*)(p3 + 128), v3b = *(const uint4*)(p3 + 136);
    edge(e0, k0a, k0b, v0a, v0b);
    edge(e1, k1a, k1b, v1a, v1b);
    edge(e2, k2a, k2b, v2a, v2b);
    edge(e3, k3a, k3b, v3a, v3b);
  }
  for (; ii < c; ii++){
    int ev = elist[start + ii];
    const u16* p = kv + (size_t)(ev >> 2) * 256 + h*16;
    uint4 ka = *(const uint4*)p,         kb = *(const uint4*)(p + 8);
    uint4 va = *(const uint4*)(p + 128), vb = *(const uint4*)(p + 136);
    edge(ev, ka, kb, va, vb);
  }

  float inv = (c > 0) ? 1.f / dsum : 0.f;
  u16 o[16];
#pragma unroll
  for (int d = 0; d < 16; d++){
    float x = acc[d] * inv;
    o[d] = f2bf(0.5f * x * (1.f + erff(x * 0.70710678118654752f)));
  }
  uint4 p0, p1;
  p0.x = o[0]|(o[1]<<16);   p0.y = o[2]|(o[3]<<16);
  p0.z = o[4]|(o[5]<<16);   p0.w = o[6]|(o[7]<<16);
  p1.x = o[8]|(o[9]<<16);   p1.y = o[10]|(o[11]<<16);
  p1.z = o[12]|(o[13]<<16); p1.w = o[14]|(o[15]<<16);
  u16* op = qg + (size_t)n * 128 + h*16;
  *(uint4*)op = p0; *(uint4*)(op + 8) = p1;
}

// ---------------- host ----------------

extern "C" void kernel_launch(void* const* d_in, const int* in_sizes, int n_in,
                              void* d_out, int out_size, void* d_ws, size_t ws_size,
                              hipStream_t stream)
{
  const float* xg   = (const float*)d_in[0];
  const float* xd   = (const float*)d_in[1];
  const float* xr_  = (const float*)d_in[2];
  const float* Wkqv = (const float*)d_in[3];
  const float* bkqv = (const float*)d_in[4];
  const float* Ak   = (const float*)d_in[5];
  const float* Av   = (const float*)d_in[6];
  const float* prel = (const float*)d_in[7];
  const float* Wout = (const float*)d_in[8];
  const float* bout = (const float*)d_in[9];
  const float* skip = (const float*)d_in[10];
  const int* ei[4] = {(const int*)d_in[11], (const int*)d_in[12],
                      (const int*)d_in[13], (const int*)d_in[14]};

  float* X = (float*)d_out;

  char* p = (char*)d_ws;
  auto alloc = [&](size_t b)->void*{ void* r = (void*)p; p += (b + 255) & ~(size_t)255; return r; };
  int*   cnt   = (int*)  alloc((size_t)NTOT * 4);
  int*   rowp  = (int*)  alloc((size_t)NTOT * 4);
  int*   cur   = (int*)  alloc((size_t)NTOT * 4);
  int*   bsum  = (int*)  alloc(512 * 4);
  int*   elist = (int*)  alloc((size_t)ETOT * 4);
  float* Weff  = (float*)alloc((size_t)8 * 32768 * 4);
  float* beff  = (float*)alloc((size_t)8 * 256 * 4);
  u16*   qg    = (u16*)  alloc((size_t)NTOT * 128 * 2);    // 20.5 MB bf16
  u16*   kv    = (u16*)  alloc((size_t)NSRC * 256 * 2);    // 61.4 MB bf16
  u16*   Xbf   = (u16*)  alloc((size_t)NTOT * 128 * 2);    // 20.5 MB bf16
  u16*   WqT   = (u16*)  alloc((size_t)6 * 16384 * 2);
  u16*   WeffT = (u16*)  alloc((size_t)8 * 32768 * 2);
  u16*   WoutT = (u16*)  alloc((size_t)6 * 16384 * 2);
  (void)ws_size; (void)in_sizes; (void)n_in; (void)out_size;

  copy_init<<<10000, 256, 0, stream>>>(xg, xd, xr_, X, Xbf);
  zero_cc<<<313, 256, 0, stream>>>(cnt, cur);

  count_all<<<(ETOT+255)/256, 256, 0, stream>>>(ei[0], ei[1], ei[2], ei[3], cnt);
  scan_partial<<<313, 256, 0, stream>>>(cnt, rowp, bsum);
  scan_block<<<1, 256, 0, stream>>>(bsum, 313);
  scan_add<<<313, 256, 0, stream>>>(rowp, bsum);
  scatter_all<<<(ETOT+255)/256, 256, 0, stream>>>(ei[0], ei[1], ei[2], ei[3], rowp, cur, elist);

  build_weff<<<dim3(128, 8), 256, 0, stream>>>(Wkqv, Ak, Av, Weff);
  build_beff<<<8, 256, 0, stream>>>(bkqv, Ak, Av, beff);
  conv_wq<<<384, 256, 0, stream>>>(Wkqv, WqT);
  conv_weff<<<1024, 256, 0, stream>>>(Weff, WeffT);
  conv_wout<<<384, 256, 0, stream>>>(Wout, WoutT);

  for (int l = 0; l < 2; l++){
    mfma_gemm_q<<<627, 256, 0, stream>>>(
        Xbf, WqT + (size_t)l*3*16384, bkqv + (size_t)l*3*384, qg);
    mfma_gemm_kv<<<dim3(2, 940), 256, 0, stream>>>(
        Xbf, WeffT + (size_t)l*4*32768, beff + (size_t)l*4*256, kv);
    attn_kernel<<<2500, 256, 0, stream>>>(qg, kv, prel + l*32, rowp, cnt, elist);
    mfma_gemm_out<<<627, 256, 0, stream>>>(
        qg, WoutT + (size_t)l*3*16384, bout + (size_t)l*3*128, skip + l*3, X, Xbf);
  }
}

// Round 4
// 467.775 us; speedup vs baseline: 1.3287x; 1.0049x over previous
//
#include <hip/hip_runtime.h>

// HGT encoder, MI355X — ROUND 12.
// R11 post-mortem: GEMMs fixed (out of top-5). attn back on top: 54us x2,
// VALU 41% / HBM 40% / occ 31% -> latency+imbalance bound. Wave time is
// max-degree over 8 nodes sharing the wave; serial elist->kv chains.
// R12: 16 threads per node (2 per head). Each sub-thread walks even/odd
// edge indices (batch-4 ILP kept), partials merged via __shfl_xor(8)
// (dsum + 16 acc). Halves per-wave iterations, doubles wave count
// (20k waves -> better tail), halves imbalance.
// Also: build_weff now emits bf16 WeffT directly (conv_weff dropped);
// conv_wq+conv_wout merged into one launch.
// MFMA layouts (guide-verified): A[m=lane&15][k=quad*8+j],
// B[k=quad*8+j][n=lane&15], D[row=quad*4+reg][col=lane&15].

#define NTOT  80000
#define ETOT  600000
#define NSRC  120000

typedef unsigned short u16;
typedef unsigned int   u32;
typedef __attribute__((ext_vector_type(8))) short short8;
typedef __attribute__((ext_vector_type(4))) float f32x4;

__device__ __forceinline__ float bf2f(u16 u){
  union { u32 i; float f; } v; v.i = ((u32)u) << 16; return v.f;
}
__device__ __forceinline__ u16 f2bf(float f){
  union { float f; u32 i; } v; v.f = f;
  u32 x = v.i;
  return (u16)((x + 0x7fffu + ((x >> 16) & 1u)) >> 16);   // RNE
}
__device__ __forceinline__ void unp4(uint4 a, float* o){
  union { u32 i; float f; } t;
  t.i = a.x << 16;        o[0]=t.f;  t.i = a.x & 0xffff0000u; o[1]=t.f;
  t.i = a.y << 16;        o[2]=t.f;  t.i = a.y & 0xffff0000u; o[3]=t.f;
  t.i = a.z << 16;        o[4]=t.f;  t.i = a.z & 0xffff0000u; o[5]=t.f;
  t.i = a.w << 16;        o[6]=t.f;  t.i = a.w & 0xffff0000u; o[7]=t.f;
}
__device__ __forceinline__ void load16bf(const u16* p, float* o){
  unp4(*(const uint4*)p, o); unp4(*(const uint4*)(p + 8), o + 8);
}

// ---------------- init: X fp32 + Xbf bf16 mirror ----------------

__global__ __launch_bounds__(256) void copy_init(
    const float* __restrict__ xg, const float* __restrict__ xd,
    const float* __restrict__ xr, float* __restrict__ X, u16* __restrict__ Xbf)
{
  int i = blockIdx.x * 256 + threadIdx.x;        // float4 units; 2,560,000 total
  if (i >= 2560000) return;
  const float* src; int off;
  if (i < 1600000)      { src = xg; off = i; }
  else if (i < 2240000) { src = xd; off = i - 1600000; }
  else                  { src = xr; off = i - 2240000; }
  float4 v = ((const float4*)src)[off];
  ((float4*)X)[i] = v;
  uint2 b;
  b.x = (u32)f2bf(v.x) | ((u32)f2bf(v.y) << 16);
  b.y = (u32)f2bf(v.z) | ((u32)f2bf(v.w) << 16);
  ((uint2*)Xbf)[i] = b;
}

__global__ __launch_bounds__(256) void zero_cc(int* __restrict__ cnt, int* __restrict__ cur){
  int i = blockIdx.x * 256 + threadIdx.x;
  if (i < NTOT){ cnt[i] = 0; cur[i] = 0; }
}

// ---------------- CSR build (fused over the 4 relations) ----------------

__global__ __launch_bounds__(256) void count_all(
    const int* __restrict__ e0, const int* __restrict__ e1,
    const int* __restrict__ e2, const int* __restrict__ e3,
    int* __restrict__ cnt)
{
  int e = blockIdx.x * 256 + threadIdx.x;
  if (e >= ETOT) return;
  const int* ei; int E, loc, offd;
  if (e < 300000)      { ei = e0; E = 300000; loc = e;          offd = 0; }
  else if (e < 450000) { ei = e1; E = 150000; loc = e - 300000; offd = 50000; }
  else if (e < 550000) { ei = e2; E = 100000; loc = e - 450000; offd = 0; }
  else                 { ei = e3; E = 50000;  loc = e - 550000; offd = 50000; }
  atomicAdd(&cnt[offd + ei[E + loc]], 1);
}

__global__ __launch_bounds__(256) void scan_partial(const int* __restrict__ cnt,
                             int* __restrict__ rowp, int* __restrict__ bsum){
  __shared__ int s[256];
  int tid = threadIdx.x;
  int i = blockIdx.x * 256 + tid;
  int v = (i < NTOT) ? cnt[i] : 0;
  s[tid] = v; __syncthreads();
  for (int off = 1; off < 256; off <<= 1){
    int t = (tid >= off) ? s[tid - off] : 0;
    __syncthreads();
    s[tid] += t;
    __syncthreads();
  }
  if (i < NTOT) rowp[i] = s[tid] - v;
  if (tid == 255) bsum[blockIdx.x] = s[255];
}

__global__ __launch_bounds__(256) void scan_block(int* __restrict__ bsum, int nb){
  __shared__ int b[512];
  __shared__ int p[256];
  int tid = threadIdx.x;
  b[tid]       = (tid < nb)       ? bsum[tid]       : 0;
  b[tid + 256] = (tid + 256 < nb) ? bsum[tid + 256] : 0;
  __syncthreads();
  int pv = b[2*tid] + b[2*tid + 1];
  p[tid] = pv; __syncthreads();
  for (int off = 1; off < 256; off <<= 1){
    int t = (tid >= off) ? p[tid - off] : 0;
    __syncthreads();
    p[tid] += t;
    __syncthreads();
  }
  int excl = p[tid] - pv;
  int e0 = excl, e1 = excl + b[2*tid];
  __syncthreads();
  if (2*tid < nb)   bsum[2*tid]     = e0;
  if (2*tid+1 < nb) bsum[2*tid + 1] = e1;
}

__global__ __launch_bounds__(256) void scan_add(int* __restrict__ rowp, const int* __restrict__ bsum){
  int i = blockIdx.x * 256 + threadIdx.x;
  if (i < NTOT) rowp[i] += bsum[i >> 8];
}

__global__ __launch_bounds__(256) void scatter_all(
    const int* __restrict__ e0, const int* __restrict__ e1,
    const int* __restrict__ e2, const int* __restrict__ e3,
    const int* __restrict__ rowp, int* __restrict__ cur,
    int* __restrict__ elist)
{
  int e = blockIdx.x * 256 + threadIdx.x;
  if (e >= ETOT) return;
  const int* ei; int E, loc, offd, rnoff, rel;
  if (e < 300000)      { ei = e0; E = 300000; loc = e;          offd = 0;     rnoff = 0;      rel = 0; }
  else if (e < 450000) { ei = e1; E = 150000; loc = e - 300000; offd = 50000; rnoff = 50000;  rel = 1; }
  else if (e < 550000) { ei = e2; E = 100000; loc = e - 450000; offd = 0;     rnoff = 100000; rel = 2; }
  else                 { ei = e3; E = 50000;  loc = e - 550000; offd = 50000; rnoff = 110000; rel = 3; }
  int src = ei[loc], dst = ei[E + loc];
  int dstg = offd + dst;
  int pos = atomicAdd(&cur[dstg], 1);
  elist[rowp[dstg] + pos] = ((rnoff + src) << 2) | rel;
}

// ---------------- fold Ak/Av into K/V weights -> bf16 WeffT directly ----------------
// WeffT[lr][n*128+k] = f2bf(sum_d Wkqv_st[k*384 + sel + d] * A[d*16 + e])

__global__ __launch_bounds__(256) void build_wefft(
    const float* __restrict__ Wkqv, const float* __restrict__ Ak,
    const float* __restrict__ Av, u16* __restrict__ WeffT)
{
  int i = blockIdx.x * 256 + threadIdx.x;          // 8*32768
  if (i >= 8*32768) return;
  int lr = i >> 15, rem = i & 32767, n = rem >> 7, k = rem & 127;
  int l = lr >> 2, r = lr & 3;
  int st = (r >= 2) ? 2 : 0;
  const float* W = Wkqv + (size_t)(l*3 + st) * 49152;
  float acc = 0.f;
  if (n < 128){
    int h = n >> 4, e = n & 15;
    const float* Am = Ak + (size_t)(l*4 + r) * 2048 + h*256;
#pragma unroll
    for (int d = 0; d < 16; d++) acc += W[k*384 + h*16 + d] * Am[d*16 + e];
  } else {
    int n2 = n - 128, h = n2 >> 4, e = n2 & 15;
    const float* Am = Av + (size_t)(l*4 + r) * 2048 + h*256;
#pragma unroll
    for (int d = 0; d < 16; d++) acc += W[k*384 + 256 + h*16 + d] * Am[d*16 + e];
  }
  WeffT[i] = f2bf(acc);
}

__global__ __launch_bounds__(256) void build_beff(
    const float* __restrict__ bkqv, const float* __restrict__ Ak,
    const float* __restrict__ Av, float* __restrict__ beff)
{
  int lr = blockIdx.x;
  int l = lr >> 2, r = lr & 3;
  int st = (r >= 2) ? 2 : 0;
  int j = threadIdx.x;
  const float* b = bkqv + (size_t)(l*3 + st) * 384;
  float acc = 0.f;
  if (j < 128){
    int h = j >> 4, e = j & 15;
    const float* Am = Ak + (size_t)(l*4 + r) * 2048 + h*256;
#pragma unroll
    for (int d = 0; d < 16; d++) acc += b[h*16 + d] * Am[d*16 + e];
  } else {
    int j2 = j - 128, h = j2 >> 4, e = j2 & 15;
    const float* Am = Av + (size_t)(l*4 + r) * 2048 + h*256;
#pragma unroll
    for (int d = 0; d < 16; d++) acc += b[256 + h*16 + d] * Am[d*16 + e];
  }
  beff[lr * 256 + j] = acc;
}

// ---------------- one-time weight transposes to bf16 BT[n][k] (Wq + Wout) ----------------

__global__ __launch_bounds__(256) void conv_w(
    const float* __restrict__ Wkqv, const float* __restrict__ Wout,
    u16* __restrict__ WqT, u16* __restrict__ WoutT)
{
  int i = blockIdx.x * 256 + threadIdx.x;          // 2 * 6*16384
  if (i >= 2*6*16384) return;
  if (i < 6*16384){
    int lt = i >> 14, rem = i & 16383, n = rem >> 7, k = rem & 127;
    WqT[i] = f2bf(Wkqv[(size_t)lt*49152 + k*384 + 128 + n]);
  } else {
    int j = i - 6*16384;
    int lt = j >> 14, rem = j & 16383, n = rem >> 7, k = rem & 127;
    WoutT[j] = f2bf(Wout[(size_t)lt*16384 + k*128 + n]);
  }
}

// ---------------- MFMA GEMM: block tile 128x128, wave tile 32x128 ----------------
// BT tile (128 n-rows x 128 k, bf16 = 32KB) staged in LDS, XOR-swizzled.

__device__ __forceinline__ void stage_bt(const u16* __restrict__ src, u16* BTl){
  int tid = threadIdx.x;
  const uint4* g = (const uint4*)src;          // 2048 uint4 = 32KB
  uint4 tmp[8];
#pragma unroll
  for (int i = 0; i < 8; i++) tmp[i] = g[tid + i*256];
#pragma unroll
  for (int i = 0; i < 8; i++){
    int L = (tid + i*256) * 16;                // linear byte in tile
    int Ls = L ^ (((L >> 8) & 7) << 4);        // swizzle: row bits 8-10 -> bits 4-6
    *(uint4*)((char*)BTl + Ls) = tmp[i];
  }
  __syncthreads();
}

__device__ __forceinline__ void gemm_core(
    const u16* __restrict__ A, const u16* BTl, int M, int bm,
    f32x4 acc[8][2])
{
  int tid = threadIdx.x;
  int lane = tid & 63, w = tid >> 6;
  int quad = lane >> 4, lm = lane & 15;
  short8 af[2][4];
#pragma unroll
  for (int mf = 0; mf < 2; mf++){
    int row = bm + w*32 + mf*16 + lm;
    if (row < M){
      const u16* ap = A + (size_t)row*128 + quad*8;
#pragma unroll
      for (int c = 0; c < 4; c++) af[mf][c] = *(const short8*)(ap + c*32);
    } else {
      short8 z = {0,0,0,0,0,0,0,0};
#pragma unroll
      for (int c = 0; c < 4; c++) af[mf][c] = z;
    }
  }
#pragma unroll
  for (int nt = 0; nt < 8; nt++)
#pragma unroll
    for (int mf = 0; mf < 2; mf++) acc[nt][mf] = (f32x4){0.f,0.f,0.f,0.f};
#pragma unroll
  for (int nt = 0; nt < 8; nt++){
    int rowb = nt*16 + lm;
    int base = rowb*256 + quad*16;
    int sw = (rowb & 7) << 4;
#pragma unroll
    for (int c = 0; c < 4; c++){
      short8 bf = *(const short8*)((const char*)BTl + ((base + c*64) ^ sw));
      acc[nt][0] = __builtin_amdgcn_mfma_f32_16x16x32_bf16(af[0][c], bf, acc[nt][0], 0, 0, 0);
      acc[nt][1] = __builtin_amdgcn_mfma_f32_16x16x32_bf16(af[1][c], bf, acc[nt][1], 0, 0, 0);
    }
  }
}

// Fused q-GEMM: all 3 node types, grid = 627, tile 128 rows.
__global__ __launch_bounds__(256) void mfma_gemm_q(
    const u16* __restrict__ Xbf, const u16* __restrict__ WqTl,
    const float* __restrict__ bl, u16* __restrict__ qg)
{
  __shared__ u16 BTl[16384];
  int by = blockIdx.x;
  int t, bm, M, roff;
  if (by < 391)      { t = 0; bm = by*128;        M = 50000; roff = 0; }
  else if (by < 548) { t = 1; bm = (by-391)*128;  M = 20000; roff = 50000; }
  else               { t = 2; bm = (by-548)*128;  M = 10000; roff = 70000; }
  stage_bt(WqTl + (size_t)t*16384, BTl);
  const u16* A = Xbf + (size_t)roff*128;
  const float* bias = bl + (size_t)t*384 + 128;
  u16* C = qg + (size_t)roff*128;
  f32x4 acc[8][2];
  gemm_core(A, BTl, M, bm, acc);
  int lane = threadIdx.x & 63, w = threadIdx.x >> 6;
  int quad = lane >> 4, lm = lane & 15;
#pragma unroll
  for (int nt = 0; nt < 8; nt++){
    int col = nt*16 + lm;
    float bb = bias[col];
#pragma unroll
    for (int mf = 0; mf < 2; mf++)
#pragma unroll
      for (int i = 0; i < 4; i++){
        int r = bm + w*32 + mf*16 + quad*4 + i;
        if (r < M) C[(size_t)r*128 + col] = f2bf(acc[nt][mf][i] + bb);
      }
  }
}

// Fused kv-GEMM: all 4 relations, grid = (2, 940), tile 128 rows x 128 cols.
__global__ __launch_bounds__(256) void mfma_gemm_kv(
    const u16* __restrict__ Xbf, const u16* __restrict__ WeffTl,
    const float* __restrict__ beffl, u16* __restrict__ kv)
{
  __shared__ u16 BTl[16384];
  int by = blockIdx.y;
  int r, bm, M, soff, ooff;
  if (by < 391)      { r = 0; bm = by*128;        M = 50000; soff = 0;     ooff = 0; }
  else if (by < 782) { r = 1; bm = (by-391)*128;  M = 50000; soff = 0;     ooff = 50000; }
  else if (by < 861) { r = 2; bm = (by-782)*128;  M = 10000; soff = 70000; ooff = 100000; }
  else               { r = 3; bm = (by-861)*128;  M = 10000; soff = 70000; ooff = 110000; }
  int bn = blockIdx.x * 128;
  stage_bt(WeffTl + (size_t)r*32768 + (size_t)bn*128, BTl);
  const u16* A = Xbf + (size_t)soff*128;
  const float* bias = beffl + (size_t)r*256;
  u16* C = kv + (size_t)ooff*256;
  f32x4 acc[8][2];
  gemm_core(A, BTl, M, bm, acc);
  int lane = threadIdx.x & 63, w = threadIdx.x >> 6;
  int quad = lane >> 4, lm = lane & 15;
#pragma unroll
  for (int nt = 0; nt < 8; nt++){
    int col = bn + nt*16 + lm;
    float bb = bias[col];
#pragma unroll
    for (int mf = 0; mf < 2; mf++)
#pragma unroll
      for (int i = 0; i < 4; i++){
        int r2 = bm + w*32 + mf*16 + quad*4 + i;
        if (r2 < M) C[(size_t)r2*256 + col] = f2bf(acc[nt][mf][i] + bb);
      }
  }
}

// Fused out-GEMM: A = G(bf16), epilogue skip+relu+residual -> X(fp32) + Xbf. grid = 627.
__global__ __launch_bounds__(256) void mfma_gemm_out(
    const u16* __restrict__ Gall, const u16* __restrict__ WoutTl,
    const float* __restrict__ bl, const float* __restrict__ skipl,
    float* __restrict__ Xall, u16* __restrict__ Xbfall)
{
  __shared__ u16 BTl[16384];
  int by = blockIdx.x;
  int t, bm, M, roff;
  if (by < 391)      { t = 0; bm = by*128;        M = 50000; roff = 0; }
  else if (by < 548) { t = 1; bm = (by-391)*128;  M = 20000; roff = 50000; }
  else               { t = 2; bm = (by-548)*128;  M = 10000; roff = 70000; }
  stage_bt(WoutTl + (size_t)t*16384, BTl);
  const u16* A = Gall + (size_t)roff*128;
  const float* bias = bl + (size_t)t*128;
  float* X = Xall + (size_t)roff*128;
  u16* Xb = Xbfall + (size_t)roff*128;
  f32x4 acc[8][2];
  gemm_core(A, BTl, M, bm, acc);
  float a_s = 1.f / (1.f + expf(-skipl[t]));
  float b_s = 1.f - a_s;
  int lane = threadIdx.x & 63, w = threadIdx.x >> 6;
  int quad = lane >> 4, lm = lane & 15;
#pragma unroll
  for (int nt = 0; nt < 8; nt++){
    int col = nt*16 + lm;
    float bb = bias[col];
#pragma unroll
    for (int mf = 0; mf < 2; mf++)
#pragma unroll
      for (int i = 0; i < 4; i++){
        int r = bm + w*32 + mf*16 + quad*4 + i;
        if (r < M){
          float* xp = X + (size_t)r*128 + col;
          float x = *xp;
          float o = acc[nt][mf][i] + bb;
          float xn = fmaxf(a_s*o + b_s*x, 0.f) + x;
          *xp = xn;
          Xb[(size_t)r*128 + col] = f2bf(xn);
        }
      }
  }
}

// ---------------- attention: 16 threads per node (2 per head) ----------------

__global__ __launch_bounds__(256) void attn_kernel(
    u16* __restrict__ qg,                   // NTOT x 128 bf16: q in, gelu(out) out
    const u16* __restrict__ kv,             // NSRC x 256 bf16: [k | v]
    const float* __restrict__ prel,         // + l*32
    const int* __restrict__ rowp, const int* __restrict__ cnt,
    const int* __restrict__ elist)
{
  int gid = blockIdx.x * 256 + threadIdx.x;
  int n = gid >> 4;                          // node
  if (n >= NTOT) return;
  int lane = threadIdx.x & 63;
  int sub = (lane >> 3) & 1;                 // edge-half
  int h = lane & 7;                          // head
  float sc0 = prel[0*8+h]*0.25f, sc1 = prel[1*8+h]*0.25f,
        sc2 = prel[2*8+h]*0.25f, sc3 = prel[3*8+h]*0.25f;
  float q[16];
  load16bf(qg + (size_t)n * 128 + h*16, q);
  float acc[16] = {};
  float dsum = 0.f;
  int start = rowp[n], c = cnt[n];

  auto edge = [&](int ev, uint4 ka, uint4 kb, uint4 va, uint4 vb){
    float ke[16], ve[16];
    unp4(ka, ke); unp4(kb, ke + 8);
    unp4(va, ve); unp4(vb, ve + 8);
    float a = 0.f;
#pragma unroll
    for (int d = 0; d < 16; d++) a += q[d] * ke[d];
    int r = ev & 3;
    float s = (r == 0) ? sc0 : (r == 1) ? sc1 : (r == 2) ? sc2 : sc3;
    float ex = expf(a * s);
    dsum += ex;
#pragma unroll
    for (int d = 0; d < 16; d++) acc[d] += ex * ve[d];
  };

  int idx = sub;                             // this sub-thread: indices sub, sub+2, ...
#pragma unroll 1
  for (; idx + 6 < c; idx += 8){             // batch of 4 edges (stride 2)
    int e0 = elist[start + idx + 0], e1 = elist[start + idx + 2],
        e2 = elist[start + idx + 4], e3 = elist[start + idx + 6];
    const u16* p0 = kv + (size_t)(e0 >> 2) * 256 + h*16;
    const u16* p1 = kv + (size_t)(e1 >> 2) * 256 + h*16;
    const u16* p2 = kv + (size_t)(e2 >> 2) * 256 + h*16;
    const u16* p3 = kv + (size_t)(e3 >> 2) * 256 + h*16;
    uint4 k0a = *(const uint4*)p0,         k0b = *(const uint4*)(p0 + 8);
    uint4 k1a = *(const uint4*)p1,         k1b = *(const uint4*)(p1 + 8);
    uint4 k2a = *(const uint4*)p2,         k2b = *(const uint4*)(p2 + 8);
    uint4 k3a = *(const uint4*)p3,         k3b = *(const uint4*)(p3 + 8);
    uint4 v0a = *(const uint4*)(p0 + 128), v0b = *(const uint4*)(p0 + 136);
    uint4 v1a = *(const uint4*)(p1 + 128), v1b = *(const uint4*)(p1 + 136);
    uint4 v2a = *(const uint4*)(p2 + 128), v2b = *(const uint4*)(p2 + 136);
    uint4 v3a = *(const uint4*)(p3 + 128), v3b = *(const uint4*)(p3 + 136);
    edge(e0, k0a, k0b, v0a, v0b);
    edge(e1, k1a, k1b, v1a, v1b);
    edge(e2, k2a, k2b, v2a, v2b);
    edge(e3, k3a, k3b, v3a, v3b);
  }
#pragma unroll 1
  for (; idx < c; idx += 2){
    int ev = elist[start + idx];
    const u16* p = kv + (size_t)(ev >> 2) * 256 + h*16;
    uint4 ka = *(const uint4*)p,         kb = *(const uint4*)(p + 8);
    uint4 va = *(const uint4*)(p + 128), vb = *(const uint4*)(p + 136);
    edge(ev, ka, kb, va, vb);
  }

  // merge the two edge-halves (lane ^ 8 = same node, same head, other sub)
  dsum += __shfl_xor(dsum, 8);
#pragma unroll
  for (int d = 0; d < 16; d++) acc[d] += __shfl_xor(acc[d], 8);

  if (sub == 0){
    float inv = (c > 0) ? 1.f / dsum : 0.f;
    u16 o[16];
#pragma unroll
    for (int d = 0; d < 16; d++){
      float x = acc[d] * inv;
      o[d] = f2bf(0.5f * x * (1.f + erff(x * 0.70710678118654752f)));
    }
    uint4 p0, p1;
    p0.x = o[0]|(o[1]<<16);   p0.y = o[2]|(o[3]<<16);
    p0.z = o[4]|(o[5]<<16);   p0.w = o[6]|(o[7]<<16);
    p1.x = o[8]|(o[9]<<16);   p1.y = o[10]|(o[11]<<16);
    p1.z = o[12]|(o[13]<<16); p1.w = o[14]|(o[15]<<16);
    u16* op = qg + (size_t)n * 128 + h*16;
    *(uint4*)op = p0; *(uint4*)(op + 8) = p1;
  }
}

// ---------------- host ----------------

extern "C" void kernel_launch(void* const* d_in, const int* in_sizes, int n_in,
                              void* d_out, int out_size, void* d_ws, size_t ws_size,
                              hipStream_t stream)
{
  const float* xg   = (const float*)d_in[0];
  const float* xd   = (const float*)d_in[1];
  const float* xr_  = (const float*)d_in[2];
  const float* Wkqv = (const float*)d_in[3];
  const float* bkqv = (const float*)d_in[4];
  const float* Ak   = (const float*)d_in[5];
  const float* Av   = (const float*)d_in[6];
  const float* prel = (const float*)d_in[7];
  const float* Wout = (const float*)d_in[8];
  const float* bout = (const float*)d_in[9];
  const float* skip = (const float*)d_in[10];
  const int* ei[4] = {(const int*)d_in[11], (const int*)d_in[12],
                      (const int*)d_in[13], (const int*)d_in[14]};

  float* X = (float*)d_out;

  char* p = (char*)d_ws;
  auto alloc = [&](size_t b)->void*{ void* r = (void*)p; p += (b + 255) & ~(size_t)255; return r; };
  int*   cnt   = (int*)  alloc((size_t)NTOT * 4);
  int*   rowp  = (int*)  alloc((size_t)NTOT * 4);
  int*   cur   = (int*)  alloc((size_t)NTOT * 4);
  int*   bsum  = (int*)  alloc(512 * 4);
  int*   elist = (int*)  alloc((size_t)ETOT * 4);
  float* beff  = (float*)alloc((size_t)8 * 256 * 4);
  u16*   qg    = (u16*)  alloc((size_t)NTOT * 128 * 2);    // 20.5 MB bf16
  u16*   kv    = (u16*)  alloc((size_t)NSRC * 256 * 2);    // 61.4 MB bf16
  u16*   Xbf   = (u16*)  alloc((size_t)NTOT * 128 * 2);    // 20.5 MB bf16
  u16*   WqT   = (u16*)  alloc((size_t)6 * 16384 * 2);
  u16*   WeffT = (u16*)  alloc((size_t)8 * 32768 * 2);
  u16*   WoutT = (u16*)  alloc((size_t)6 * 16384 * 2);
  (void)ws_size; (void)in_sizes; (void)n_in; (void)out_size;

  copy_init<<<10000, 256, 0, stream>>>(xg, xd, xr_, X, Xbf);
  zero_cc<<<313, 256, 0, stream>>>(cnt, cur);

  count_all<<<(ETOT+255)/256, 256, 0, stream>>>(ei[0], ei[1], ei[2], ei[3], cnt);
  scan_partial<<<313, 256, 0, stream>>>(cnt, rowp, bsum);
  scan_block<<<1, 256, 0, stream>>>(bsum, 313);
  scan_add<<<313, 256, 0, stream>>>(rowp, bsum);
  scatter_all<<<(ETOT+255)/256, 256, 0, stream>>>(ei[0], ei[1], ei[2], ei[3], rowp, cur, elist);

  build_wefft<<<1024, 256, 0, stream>>>(Wkqv, Ak, Av, WeffT);
  build_beff<<<8, 256, 0, stream>>>(bkqv, Ak, Av, beff);
  conv_w<<<768, 256, 0, stream>>>(Wkqv, Wout, WqT, WoutT);

  for (int l = 0; l < 2; l++){
    mfma_gemm_q<<<627, 256, 0, stream>>>(
        Xbf, WqT + (size_t)l*3*16384, bkqv + (size_t)l*3*384, qg);
    mfma_gemm_kv<<<dim3(2, 940), 256, 0, stream>>>(
        Xbf, WeffT + (size_t)l*4*32768, beff + (size_t)l*4*256, kv);
    attn_kernel<<<5000, 256, 0, stream>>>(qg, kv, prel + l*32, rowp, cnt, elist);
    mfma_gemm_out<<<627, 256, 0, stream>>>(
        qg, WoutT + (size_t)l*3*16384, bout + (size_t)l*3*128, skip + l*3, X, Xbf);
  }
}

// Round 5
// 454.771 us; speedup vs baseline: 1.3667x; 1.0286x over previous
//
#include <hip/hip_runtime.h>

// HGT encoder, MI355X — ROUND 13.
// R12 post-mortem: attn pinned at 53us across ILP (R9) and TLP (R12) changes,
// miss-BW flat at 3.2 TB/s -> outstanding-miss-capacity limited random gather;
// declared ceiling. This round targets the GEMMs:
//  1. Wave tile 32x128 -> 16x128 (VGPR ~70): 64-row blocks, 2x grid, ~5
//     waves/SIMD resident (was 2.45) -> latency actually hidden.
//  2. q-GEMM + kv-GEMM fused into ONE dispatch (independent work, 5008
//     blocks) -> one ramp/drain, concurrent execution.
//  3. Prep launches merged: copy_init+zero_cc; wefft+beff+conv_w.
// attn kept (R12 structure). MFMA layouts unchanged (guide-verified).

#define NTOT  80000
#define ETOT  600000
#define NSRC  120000

typedef unsigned short u16;
typedef unsigned int   u32;
typedef __attribute__((ext_vector_type(8))) short short8;
typedef __attribute__((ext_vector_type(4))) float f32x4;

__device__ __forceinline__ float bf2f(u16 u){
  union { u32 i; float f; } v; v.i = ((u32)u) << 16; return v.f;
}
__device__ __forceinline__ u16 f2bf(float f){
  union { float f; u32 i; } v; v.f = f;
  u32 x = v.i;
  return (u16)((x + 0x7fffu + ((x >> 16) & 1u)) >> 16);   // RNE
}
__device__ __forceinline__ void unp4(uint4 a, float* o){
  union { u32 i; float f; } t;
  t.i = a.x << 16;        o[0]=t.f;  t.i = a.x & 0xffff0000u; o[1]=t.f;
  t.i = a.y << 16;        o[2]=t.f;  t.i = a.y & 0xffff0000u; o[3]=t.f;
  t.i = a.z << 16;        o[4]=t.f;  t.i = a.z & 0xffff0000u; o[5]=t.f;
  t.i = a.w << 16;        o[6]=t.f;  t.i = a.w & 0xffff0000u; o[7]=t.f;
}
__device__ __forceinline__ void load16bf(const u16* p, float* o){
  unp4(*(const uint4*)p, o); unp4(*(const uint4*)(p + 8), o + 8);
}

// ---------------- init: X fp32 + Xbf bf16 mirror + zero cnt/cur ----------------

__global__ __launch_bounds__(256) void init_all(
    const float* __restrict__ xg, const float* __restrict__ xd,
    const float* __restrict__ xr, float* __restrict__ X, u16* __restrict__ Xbf,
    int* __restrict__ cnt, int* __restrict__ cur)
{
  int i = blockIdx.x * 256 + threadIdx.x;
  if (i < 2560000){
    const float* src; int off;
    if (i < 1600000)      { src = xg; off = i; }
    else if (i < 2240000) { src = xd; off = i - 1600000; }
    else                  { src = xr; off = i - 2240000; }
    float4 v = ((const float4*)src)[off];
    ((float4*)X)[i] = v;
    uint2 b;
    b.x = (u32)f2bf(v.x) | ((u32)f2bf(v.y) << 16);
    b.y = (u32)f2bf(v.z) | ((u32)f2bf(v.w) << 16);
    ((uint2*)Xbf)[i] = b;
  } else {
    int j = i - 2560000;
    if (j < NTOT){ cnt[j] = 0; cur[j] = 0; }
  }
}

// ---------------- CSR build (fused over the 4 relations) ----------------

__global__ __launch_bounds__(256) void count_all(
    const int* __restrict__ e0, const int* __restrict__ e1,
    const int* __restrict__ e2, const int* __restrict__ e3,
    int* __restrict__ cnt)
{
  int e = blockIdx.x * 256 + threadIdx.x;
  if (e >= ETOT) return;
  const int* ei; int E, loc, offd;
  if (e < 300000)      { ei = e0; E = 300000; loc = e;          offd = 0; }
  else if (e < 450000) { ei = e1; E = 150000; loc = e - 300000; offd = 50000; }
  else if (e < 550000) { ei = e2; E = 100000; loc = e - 450000; offd = 0; }
  else                 { ei = e3; E = 50000;  loc = e - 550000; offd = 50000; }
  atomicAdd(&cnt[offd + ei[E + loc]], 1);
}

__global__ __launch_bounds__(256) void scan_partial(const int* __restrict__ cnt,
                             int* __restrict__ rowp, int* __restrict__ bsum){
  __shared__ int s[256];
  int tid = threadIdx.x;
  int i = blockIdx.x * 256 + tid;
  int v = (i < NTOT) ? cnt[i] : 0;
  s[tid] = v; __syncthreads();
  for (int off = 1; off < 256; off <<= 1){
    int t = (tid >= off) ? s[tid - off] : 0;
    __syncthreads();
    s[tid] += t;
    __syncthreads();
  }
  if (i < NTOT) rowp[i] = s[tid] - v;
  if (tid == 255) bsum[blockIdx.x] = s[255];
}

__global__ __launch_bounds__(256) void scan_block(int* __restrict__ bsum, int nb){
  __shared__ int b[512];
  __shared__ int p[256];
  int tid = threadIdx.x;
  b[tid]       = (tid < nb)       ? bsum[tid]       : 0;
  b[tid + 256] = (tid + 256 < nb) ? bsum[tid + 256] : 0;
  __syncthreads();
  int pv = b[2*tid] + b[2*tid + 1];
  p[tid] = pv; __syncthreads();
  for (int off = 1; off < 256; off <<= 1){
    int t = (tid >= off) ? p[tid - off] : 0;
    __syncthreads();
    p[tid] += t;
    __syncthreads();
  }
  int excl = p[tid] - pv;
  int e0 = excl, e1 = excl + b[2*tid];
  __syncthreads();
  if (2*tid < nb)   bsum[2*tid]     = e0;
  if (2*tid+1 < nb) bsum[2*tid + 1] = e1;
}

__global__ __launch_bounds__(256) void scan_add(int* __restrict__ rowp, const int* __restrict__ bsum){
  int i = blockIdx.x * 256 + threadIdx.x;
  if (i < NTOT) rowp[i] += bsum[i >> 8];
}

__global__ __launch_bounds__(256) void scatter_all(
    const int* __restrict__ e0, const int* __restrict__ e1,
    const int* __restrict__ e2, const int* __restrict__ e3,
    const int* __restrict__ rowp, int* __restrict__ cur,
    int* __restrict__ elist)
{
  int e = blockIdx.x * 256 + threadIdx.x;
  if (e >= ETOT) return;
  const int* ei; int E, loc, offd, rnoff, rel;
  if (e < 300000)      { ei = e0; E = 300000; loc = e;          offd = 0;     rnoff = 0;      rel = 0; }
  else if (e < 450000) { ei = e1; E = 150000; loc = e - 300000; offd = 50000; rnoff = 50000;  rel = 1; }
  else if (e < 550000) { ei = e2; E = 100000; loc = e - 450000; offd = 0;     rnoff = 100000; rel = 2; }
  else                 { ei = e3; E = 50000;  loc = e - 550000; offd = 50000; rnoff = 110000; rel = 3; }
  int src = ei[loc], dst = ei[E + loc];
  int dstg = offd + dst;
  int pos = atomicAdd(&cur[dstg], 1);
  elist[rowp[dstg] + pos] = ((rnoff + src) << 2) | rel;
}

// ---------------- merged weight prep ----------------
// seg 0: WeffT[lr][n*128+k] (8*32768)  seg 1: WqT/WoutT (2*6*16384)  seg 2: beff (2048)

__global__ __launch_bounds__(256) void wprep_all(
    const float* __restrict__ Wkqv, const float* __restrict__ bkqv,
    const float* __restrict__ Ak, const float* __restrict__ Av,
    const float* __restrict__ Wout,
    u16* __restrict__ WeffT, u16* __restrict__ WqT, u16* __restrict__ WoutT,
    float* __restrict__ beff)
{
  int i = blockIdx.x * 256 + threadIdx.x;
  if (i < 8*32768){
    int lr = i >> 15, rem = i & 32767, n = rem >> 7, k = rem & 127;
    int l = lr >> 2, r = lr & 3;
    int st = (r >= 2) ? 2 : 0;
    const float* W = Wkqv + (size_t)(l*3 + st) * 49152;
    float acc = 0.f;
    if (n < 128){
      int h = n >> 4, e = n & 15;
      const float* Am = Ak + (size_t)(l*4 + r) * 2048 + h*256;
#pragma unroll
      for (int d = 0; d < 16; d++) acc += W[k*384 + h*16 + d] * Am[d*16 + e];
    } else {
      int n2 = n - 128, h = n2 >> 4, e = n2 & 15;
      const float* Am = Av + (size_t)(l*4 + r) * 2048 + h*256;
#pragma unroll
      for (int d = 0; d < 16; d++) acc += W[k*384 + 256 + h*16 + d] * Am[d*16 + e];
    }
    WeffT[i] = f2bf(acc);
    return;
  }
  int j = i - 8*32768;
  if (j < 2*6*16384){
    if (j < 6*16384){
      int lt = j >> 14, rem = j & 16383, n = rem >> 7, k = rem & 127;
      WqT[j] = f2bf(Wkqv[(size_t)lt*49152 + k*384 + 128 + n]);
    } else {
      int j2 = j - 6*16384;
      int lt = j2 >> 14, rem = j2 & 16383, n = rem >> 7, k = rem & 127;
      WoutT[j2] = f2bf(Wout[(size_t)lt*16384 + k*128 + n]);
    }
    return;
  }
  int m = j - 2*6*16384;                 // 0..2047: beff
  if (m >= 2048) return;
  int lr = m >> 8, jj = m & 255;
  int l = lr >> 2, r = lr & 3;
  int st = (r >= 2) ? 2 : 0;
  const float* b = bkqv + (size_t)(l*3 + st) * 384;
  float acc = 0.f;
  if (jj < 128){
    int h = jj >> 4, e = jj & 15;
    const float* Am = Ak + (size_t)(l*4 + r) * 2048 + h*256;
#pragma unroll
    for (int d = 0; d < 16; d++) acc += b[h*16 + d] * Am[d*16 + e];
  } else {
    int j2 = jj - 128, h = j2 >> 4, e = j2 & 15;
    const float* Am = Av + (size_t)(l*4 + r) * 2048 + h*256;
#pragma unroll
    for (int d = 0; d < 16; d++) acc += b[256 + h*16 + d] * Am[d*16 + e];
  }
  beff[lr * 256 + jj] = acc;
}

// ---------------- MFMA GEMM: block tile 64x128, wave tile 16x128 ----------------
// BT tile (128 n-rows x 128 k, bf16 = 32KB) staged in LDS, XOR-swizzled.

__device__ __forceinline__ void stage_bt(const u16* __restrict__ src, u16* BTl){
  int tid = threadIdx.x;
  const uint4* g = (const uint4*)src;          // 2048 uint4 = 32KB
  uint4 tmp[8];
#pragma unroll
  for (int i = 0; i < 8; i++) tmp[i] = g[tid + i*256];
#pragma unroll
  for (int i = 0; i < 8; i++){
    int L = (tid + i*256) * 16;                // linear byte in tile
    int Ls = L ^ (((L >> 8) & 7) << 4);        // swizzle: row bits 8-10 -> bits 4-6
    *(uint4*)((char*)BTl + Ls) = tmp[i];
  }
  __syncthreads();
}

__device__ __forceinline__ void gemm_core16(
    const u16* __restrict__ A, const u16* BTl, int M, int bm,
    f32x4 acc[8])
{
  int tid = threadIdx.x;
  int lane = tid & 63, w = tid >> 6;
  int quad = lane >> 4, lm = lane & 15;
  int row = bm + w*16 + lm;
  short8 af[4];
  if (row < M){
    const u16* ap = A + (size_t)row*128 + quad*8;
#pragma unroll
    for (int c = 0; c < 4; c++) af[c] = *(const short8*)(ap + c*32);
  } else {
    short8 z = {0,0,0,0,0,0,0,0};
#pragma unroll
    for (int c = 0; c < 4; c++) af[c] = z;
  }
#pragma unroll
  for (int nt = 0; nt < 8; nt++) acc[nt] = (f32x4){0.f,0.f,0.f,0.f};
#pragma unroll
  for (int nt = 0; nt < 8; nt++){
    int rowb = nt*16 + lm;
    int base = rowb*256 + quad*16;
    int sw = (rowb & 7) << 4;
#pragma unroll
    for (int c = 0; c < 4; c++){
      short8 bf = *(const short8*)((const char*)BTl + ((base + c*64) ^ sw));
      acc[nt] = __builtin_amdgcn_mfma_f32_16x16x32_bf16(af[c], bf, acc[nt], 0, 0, 0);
    }
  }
}

// Fused q+kv GEMM, one dispatch. 64-row tiles.
// by [0,1252): q  — t0 [0,782) t1 [782,1095) t2 [1095,1252)
// by [1252,1252+3756): kv — idx=(by-1252); bn = (idx<1878)?0:128; tile=idx%1878;
//   r0 [0,782) r1 [782,1564) r2 [1564,1721) r3 [1721,1878)
__global__ __launch_bounds__(256) void mfma_gemm_qkv(
    const u16* __restrict__ Xbf,
    const u16* __restrict__ WqTl, const float* __restrict__ bl,
    const u16* __restrict__ WeffTl, const float* __restrict__ beffl,
    u16* __restrict__ qg, u16* __restrict__ kv)
{
  __shared__ u16 BTl[16384];
  int by = blockIdx.x;
  const u16* A; const u16* BT; const float* bias;
  u16* C; int ldc, bm, M, bn;
  if (by < 1252){
    int t, roff;
    if (by < 782)       { t = 0; bm = by*64;         M = 50000; roff = 0; }
    else if (by < 1095) { t = 1; bm = (by-782)*64;   M = 20000; roff = 50000; }
    else                { t = 2; bm = (by-1095)*64;  M = 10000; roff = 70000; }
    A = Xbf + (size_t)roff*128;
    BT = WqTl + (size_t)t*16384;
    bias = bl + (size_t)t*384 + 128;
    C = qg + (size_t)roff*128; ldc = 128; bn = 0;
  } else {
    int idx = by - 1252;
    bn = (idx < 1878) ? 0 : 128;
    int tile = (idx < 1878) ? idx : idx - 1878;
    int r, soff, ooff;
    if (tile < 782)       { r = 0; bm = tile*64;        M = 50000; soff = 0;     ooff = 0; }
    else if (tile < 1564) { r = 1; bm = (tile-782)*64;  M = 50000; soff = 0;     ooff = 50000; }
    else if (tile < 1721) { r = 2; bm = (tile-1564)*64; M = 10000; soff = 70000; ooff = 100000; }
    else                  { r = 3; bm = (tile-1721)*64; M = 10000; soff = 70000; ooff = 110000; }
    A = Xbf + (size_t)soff*128;
    BT = WeffTl + (size_t)r*32768 + (size_t)bn*128;
    bias = beffl + (size_t)r*256 + bn;
    C = kv + (size_t)ooff*256 + bn; ldc = 256;
  }
  stage_bt(BT, BTl);
  f32x4 acc[8];
  gemm_core16(A, BTl, M, bm, acc);
  int lane = threadIdx.x & 63, w = threadIdx.x >> 6;
  int quad = lane >> 4, lm = lane & 15;
#pragma unroll
  for (int nt = 0; nt < 8; nt++){
    int col = nt*16 + lm;
    float bb = bias[col];
#pragma unroll
    for (int i = 0; i < 4; i++){
      int r = bm + w*16 + quad*4 + i;
      if (r < M) C[(size_t)r*ldc + col] = f2bf(acc[nt][i] + bb);
    }
  }
}

// Fused out-GEMM: A = G(bf16), epilogue skip+relu+residual -> X(fp32) + Xbf. grid = 1252.
__global__ __launch_bounds__(256) void mfma_gemm_out(
    const u16* __restrict__ Gall, const u16* __restrict__ WoutTl,
    const float* __restrict__ bl, const float* __restrict__ skipl,
    float* __restrict__ Xall, u16* __restrict__ Xbfall)
{
  __shared__ u16 BTl[16384];
  int by = blockIdx.x;
  int t, bm, M, roff;
  if (by < 782)       { t = 0; bm = by*64;         M = 50000; roff = 0; }
  else if (by < 1095) { t = 1; bm = (by-782)*64;   M = 20000; roff = 50000; }
  else                { t = 2; bm = (by-1095)*64;  M = 10000; roff = 70000; }
  stage_bt(WoutTl + (size_t)t*16384, BTl);
  const u16* A = Gall + (size_t)roff*128;
  const float* bias = bl + (size_t)t*128;
  float* X = Xall + (size_t)roff*128;
  u16* Xb = Xbfall + (size_t)roff*128;
  f32x4 acc[8];
  gemm_core16(A, BTl, M, bm, acc);
  float a_s = 1.f / (1.f + expf(-skipl[t]));
  float b_s = 1.f - a_s;
  int lane = threadIdx.x & 63, w = threadIdx.x >> 6;
  int quad = lane >> 4, lm = lane & 15;
#pragma unroll
  for (int nt = 0; nt < 8; nt++){
    int col = nt*16 + lm;
    float bb = bias[col];
#pragma unroll
    for (int i = 0; i < 4; i++){
      int r = bm + w*16 + quad*4 + i;
      if (r < M){
        float* xp = X + (size_t)r*128 + col;
        float x = *xp;
        float o = acc[nt][i] + bb;
        float xn = fmaxf(a_s*o + b_s*x, 0.f) + x;
        *xp = xn;
        Xb[(size_t)r*128 + col] = f2bf(xn);
      }
    }
  }
}

// ---------------- attention: 16 threads per node (2 per head) ----------------

__global__ __launch_bounds__(256) void attn_kernel(
    u16* __restrict__ qg,                   // NTOT x 128 bf16: q in, gelu(out) out
    const u16* __restrict__ kv,             // NSRC x 256 bf16: [k | v]
    const float* __restrict__ prel,         // + l*32
    const int* __restrict__ rowp, const int* __restrict__ cnt,
    const int* __restrict__ elist)
{
  int gid = blockIdx.x * 256 + threadIdx.x;
  int n = gid >> 4;                          // node
  if (n >= NTOT) return;
  int lane = threadIdx.x & 63;
  int sub = (lane >> 3) & 1;                 // edge-half
  int h = lane & 7;                          // head
  float sc0 = prel[0*8+h]*0.25f, sc1 = prel[1*8+h]*0.25f,
        sc2 = prel[2*8+h]*0.25f, sc3 = prel[3*8+h]*0.25f;
  float q[16];
  load16bf(qg + (size_t)n * 128 + h*16, q);
  float acc[16] = {};
  float dsum = 0.f;
  int start = rowp[n], c = cnt[n];

  auto edge = [&](int ev, uint4 ka, uint4 kb, uint4 va, uint4 vb){
    float ke[16], ve[16];
    unp4(ka, ke); unp4(kb, ke + 8);
    unp4(va, ve); unp4(vb, ve + 8);
    float a = 0.f;
#pragma unroll
    for (int d = 0; d < 16; d++) a += q[d] * ke[d];
    int r = ev & 3;
    float s = (r == 0) ? sc0 : (r == 1) ? sc1 : (r == 2) ? sc2 : sc3;
    float ex = expf(a * s);
    dsum += ex;
#pragma unroll
    for (int d = 0; d < 16; d++) acc[d] += ex * ve[d];
  };

  int idx = sub;                             // this sub-thread: indices sub, sub+2, ...
#pragma unroll 1
  for (; idx + 6 < c; idx += 8){             // batch of 4 edges (stride 2)
    int e0 = elist[start + idx + 0], e1 = elist[start + idx + 2],
        e2 = elist[start + idx + 4], e3 = elist[start + idx + 6];
    const u16* p0 = kv + (size_t)(e0 >> 2) * 256 + h*16;
    const u16* p1 = kv + (size_t)(e1 >> 2) * 256 + h*16;
    const u16* p2 = kv + (size_t)(e2 >> 2) * 256 + h*16;
    const u16* p3 = kv + (size_t)(e3 >> 2) * 256 + h*16;
    uint4 k0a = *(const uint4*)p0,         k0b = *(const uint4*)(p0 + 8);
    uint4 k1a = *(const uint4*)p1,         k1b = *(const uint4*)(p1 + 8);
    uint4 k2a = *(const uint4*)p2,         k2b = *(const uint4*)(p2 + 8);
    uint4 k3a = *(const uint4*)p3,         k3b = *(const uint4*)(p3 + 8);
    uint4 v0a = *(const uint4*)(p0 + 128), v0b = *(const uint4*)(p0 + 136);
    uint4 v1a = *(const uint4*)(p1 + 128), v1b = *(const uint4*)(p1 + 136);
    uint4 v2a = *(const uint4*)(p2 + 128), v2b = *(const uint4*)(p2 + 136);
    uint4 v3a = *(const uint4*)(p3 + 128), v3b = *(const uint4*)(p3 + 136);
    edge(e0, k0a, k0b, v0a, v0b);
    edge(e1, k1a, k1b, v1a, v1b);
    edge(e2, k2a, k2b, v2a, v2b);
    edge(e3, k3a, k3b, v3a, v3b);
  }
#pragma unroll 1
  for (; idx < c; idx += 2){
    int ev = elist[start + idx];
    const u16* p = kv + (size_t)(ev >> 2) * 256 + h*16;
    uint4 ka = *(const uint4*)p,         kb = *(const uint4*)(p + 8);
    uint4 va = *(const uint4*)(p + 128), vb = *(const uint4*)(p + 136);
    edge(ev, ka, kb, va, vb);
  }

  // merge the two edge-halves (lane ^ 8 = same node, same head, other sub)
  dsum += __shfl_xor(dsum, 8);
#pragma unroll
  for (int d = 0; d < 16; d++) acc[d] += __shfl_xor(acc[d], 8);

  if (sub == 0){
    float inv = (c > 0) ? 1.f / dsum : 0.f;
    u16 o[16];
#pragma unroll
    for (int d = 0; d < 16; d++){
      float x = acc[d] * inv;
      o[d] = f2bf(0.5f * x * (1.f + erff(x * 0.70710678118654752f)));
    }
    uint4 p0, p1;
    p0.x = o[0]|(o[1]<<16);   p0.y = o[2]|(o[3]<<16);
    p0.z = o[4]|(o[5]<<16);   p0.w = o[6]|(o[7]<<16);
    p1.x = o[8]|(o[9]<<16);   p1.y = o[10]|(o[11]<<16);
    p1.z = o[12]|(o[13]<<16); p1.w = o[14]|(o[15]<<16);
    u16* op = qg + (size_t)n * 128 + h*16;
    *(uint4*)op = p0; *(uint4*)(op + 8) = p1;
  }
}

// ---------------- host ----------------

extern "C" void kernel_launch(void* const* d_in, const int* in_sizes, int n_in,
                              void* d_out, int out_size, void* d_ws, size_t ws_size,
                              hipStream_t stream)
{
  const float* xg   = (const float*)d_in[0];
  const float* xd   = (const float*)d_in[1];
  const float* xr_  = (const float*)d_in[2];
  const float* Wkqv = (const float*)d_in[3];
  const float* bkqv = (const float*)d_in[4];
  const float* Ak   = (const float*)d_in[5];
  const float* Av   = (const float*)d_in[6];
  const float* prel = (const float*)d_in[7];
  const float* Wout = (const float*)d_in[8];
  const float* bout = (const float*)d_in[9];
  const float* skip = (const float*)d_in[10];
  const int* ei[4] = {(const int*)d_in[11], (const int*)d_in[12],
                      (const int*)d_in[13], (const int*)d_in[14]};

  float* X = (float*)d_out;

  char* p = (char*)d_ws;
  auto alloc = [&](size_t b)->void*{ void* r = (void*)p; p += (b + 255) & ~(size_t)255; return r; };
  int*   cnt   = (int*)  alloc((size_t)NTOT * 4);
  int*   rowp  = (int*)  alloc((size_t)NTOT * 4);
  int*   cur   = (int*)  alloc((size_t)NTOT * 4);
  int*   bsum  = (int*)  alloc(512 * 4);
  int*   elist = (int*)  alloc((size_t)ETOT * 4);
  float* beff  = (float*)alloc((size_t)8 * 256 * 4);
  u16*   qg    = (u16*)  alloc((size_t)NTOT * 128 * 2);    // 20.5 MB bf16
  u16*   kv    = (u16*)  alloc((size_t)NSRC * 256 * 2);    // 61.4 MB bf16
  u16*   Xbf   = (u16*)  alloc((size_t)NTOT * 128 * 2);    // 20.5 MB bf16
  u16*   WqT   = (u16*)  alloc((size_t)6 * 16384 * 2);
  u16*   WeffT = (u16*)  alloc((size_t)8 * 32768 * 2);
  u16*   WoutT = (u16*)  alloc((size_t)6 * 16384 * 2);
  (void)ws_size; (void)in_sizes; (void)n_in; (void)out_size;

  // copy_init (2.56M) + zero cnt/cur (80K)
  init_all<<<(2560000+NTOT+255)/256, 256, 0, stream>>>(xg, xd, xr_, X, Xbf, cnt, cur);

  count_all<<<(ETOT+255)/256, 256, 0, stream>>>(ei[0], ei[1], ei[2], ei[3], cnt);
  scan_partial<<<313, 256, 0, stream>>>(cnt, rowp, bsum);
  scan_block<<<1, 256, 0, stream>>>(bsum, 313);
  scan_add<<<313, 256, 0, stream>>>(rowp, bsum);
  scatter_all<<<(ETOT+255)/256, 256, 0, stream>>>(ei[0], ei[1], ei[2], ei[3], rowp, cur, elist);

  // WeffT (262144) + WqT/WoutT (196608) + beff (2048)
  wprep_all<<<(8*32768 + 2*6*16384 + 2048 + 255)/256, 256, 0, stream>>>(
      Wkqv, bkqv, Ak, Av, Wout, WeffT, WqT, WoutT, beff);

  for (int l = 0; l < 2; l++){
    mfma_gemm_qkv<<<1252 + 3756, 256, 0, stream>>>(
        Xbf,
        WqT + (size_t)l*3*16384, bkqv + (size_t)l*3*384,
        WeffT + (size_t)l*4*32768, beff + (size_t)l*4*256,
        qg, kv);
    attn_kernel<<<5000, 256, 0, stream>>>(qg, kv, prel + l*32, rowp, cnt, elist);
    mfma_gemm_out<<<1252, 256, 0, stream>>>(
        qg, WoutT + (size_t)l*3*16384, bout + (size_t)l*3*128, skip + l*3, X, Xbf);
  }
}

// Round 6
// 420.886 us; speedup vs baseline: 1.4767x; 1.0805x over previous
//
#include <hip/hip_runtime.h>

// HGT encoder, MI355X — ROUND 14.
// R13 post-mortem: attn = 53us across 3 structures with dur == FETCH/3.2TB/s
// -> random-gather HBM efficiency wall (512B random chunks ~50% of streaming
// BW). attn is at its floor; frozen. This round removes plumbing overhead:
//  1. CSR scan machinery (count + 3-phase scan + scatter = 5 kernels) ->
//     ONE direct-scatter into padded elist[node*128 + pos] (mean degree ~8-10,
//     P(deg>127) < 1e-90; guarded anyway). cnt doubles as the atomic cursor.
//  2. init_all + wprep_all merged into one mega-prep dispatch (range-split).
//  3. Final out-GEMM skips the dead Xbf write (layer 1 output unused).
// Dispatches 13 -> 8. attn/GEMM structures unchanged (R13, verified).
// MFMA layouts (guide-verified): A[m=lane&15][k=quad*8+j],
// B[k=quad*8+j][n=lane&15], D[row=quad*4+reg][col=lane&15].

#define NTOT  80000
#define ETOT  600000
#define NSRC  120000
#define SLOTS 128

typedef unsigned short u16;
typedef unsigned int   u32;
typedef __attribute__((ext_vector_type(8))) short short8;
typedef __attribute__((ext_vector_type(4))) float f32x4;

__device__ __forceinline__ float bf2f(u16 u){
  union { u32 i; float f; } v; v.i = ((u32)u) << 16; return v.f;
}
__device__ __forceinline__ u16 f2bf(float f){
  union { float f; u32 i; } v; v.f = f;
  u32 x = v.i;
  return (u16)((x + 0x7fffu + ((x >> 16) & 1u)) >> 16);   // RNE
}
__device__ __forceinline__ void unp4(uint4 a, float* o){
  union { u32 i; float f; } t;
  t.i = a.x << 16;        o[0]=t.f;  t.i = a.x & 0xffff0000u; o[1]=t.f;
  t.i = a.y << 16;        o[2]=t.f;  t.i = a.y & 0xffff0000u; o[3]=t.f;
  t.i = a.z << 16;        o[4]=t.f;  t.i = a.z & 0xffff0000u; o[5]=t.f;
  t.i = a.w << 16;        o[6]=t.f;  t.i = a.w & 0xffff0000u; o[7]=t.f;
}
__device__ __forceinline__ void load16bf(const u16* p, float* o){
  unp4(*(const uint4*)p, o); unp4(*(const uint4*)(p + 8), o + 8);
}

// ---------------- mega prep: X/Xbf init + cnt zero + WeffT/WqT/WoutT/beff ----------------
// ranges: [0,2560000) X/Xbf   [.., +80000) cnt=0   [.., +262144) WeffT
//         [.., +196608) WqT/WoutT   [.., +2048) beff

#define PR0 2560000
#define PR1 (PR0 + NTOT)
#define PR2 (PR1 + 8*32768)
#define PR3 (PR2 + 2*6*16384)
#define PR4 (PR3 + 2048)

__global__ __launch_bounds__(256) void prep_all(
    const float* __restrict__ xg, const float* __restrict__ xd,
    const float* __restrict__ xr, float* __restrict__ X, u16* __restrict__ Xbf,
    int* __restrict__ cnt,
    const float* __restrict__ Wkqv, const float* __restrict__ bkqv,
    const float* __restrict__ Ak, const float* __restrict__ Av,
    const float* __restrict__ Wout,
    u16* __restrict__ WeffT, u16* __restrict__ WqT, u16* __restrict__ WoutT,
    float* __restrict__ beff)
{
  int i = blockIdx.x * 256 + threadIdx.x;
  if (i < PR0){
    const float* src; int off;
    if (i < 1600000)      { src = xg; off = i; }
    else if (i < 2240000) { src = xd; off = i - 1600000; }
    else                  { src = xr; off = i - 2240000; }
    float4 v = ((const float4*)src)[off];
    ((float4*)X)[i] = v;
    uint2 b;
    b.x = (u32)f2bf(v.x) | ((u32)f2bf(v.y) << 16);
    b.y = (u32)f2bf(v.z) | ((u32)f2bf(v.w) << 16);
    ((uint2*)Xbf)[i] = b;
    return;
  }
  if (i < PR1){ cnt[i - PR0] = 0; return; }
  if (i < PR2){
    int j = i - PR1;
    int lr = j >> 15, rem = j & 32767, n = rem >> 7, k = rem & 127;
    int l = lr >> 2, r = lr & 3;
    int st = (r >= 2) ? 2 : 0;
    const float* W = Wkqv + (size_t)(l*3 + st) * 49152;
    float acc = 0.f;
    if (n < 128){
      int h = n >> 4, e = n & 15;
      const float* Am = Ak + (size_t)(l*4 + r) * 2048 + h*256;
#pragma unroll
      for (int d = 0; d < 16; d++) acc += W[k*384 + h*16 + d] * Am[d*16 + e];
    } else {
      int n2 = n - 128, h = n2 >> 4, e = n2 & 15;
      const float* Am = Av + (size_t)(l*4 + r) * 2048 + h*256;
#pragma unroll
      for (int d = 0; d < 16; d++) acc += W[k*384 + 256 + h*16 + d] * Am[d*16 + e];
    }
    WeffT[j] = f2bf(acc);
    return;
  }
  if (i < PR3){
    int j = i - PR2;
    if (j < 6*16384){
      int lt = j >> 14, rem = j & 16383, n = rem >> 7, k = rem & 127;
      WqT[j] = f2bf(Wkqv[(size_t)lt*49152 + k*384 + 128 + n]);
    } else {
      int j2 = j - 6*16384;
      int lt = j2 >> 14, rem = j2 & 16383, n = rem >> 7, k = rem & 127;
      WoutT[j2] = f2bf(Wout[(size_t)lt*16384 + k*128 + n]);
    }
    return;
  }
  if (i < PR4){
    int m = i - PR3;
    int lr = m >> 8, jj = m & 255;
    int l = lr >> 2, r = lr & 3;
    int st = (r >= 2) ? 2 : 0;
    const float* b = bkqv + (size_t)(l*3 + st) * 384;
    float acc = 0.f;
    if (jj < 128){
      int h = jj >> 4, e = jj & 15;
      const float* Am = Ak + (size_t)(l*4 + r) * 2048 + h*256;
#pragma unroll
      for (int d = 0; d < 16; d++) acc += b[h*16 + d] * Am[d*16 + e];
    } else {
      int j2 = jj - 128, h = j2 >> 4, e = j2 & 15;
      const float* Am = Av + (size_t)(l*4 + r) * 2048 + h*256;
#pragma unroll
      for (int d = 0; d < 16; d++) acc += b[256 + h*16 + d] * Am[d*16 + e];
    }
    beff[lr * 256 + jj] = acc;
  }
}

// ---------------- direct scatter into padded elist (128 slots / node) ----------------

__global__ __launch_bounds__(256) void scatter_direct(
    const int* __restrict__ e0, const int* __restrict__ e1,
    const int* __restrict__ e2, const int* __restrict__ e3,
    int* __restrict__ cnt, int* __restrict__ elist)
{
  int e = blockIdx.x * 256 + threadIdx.x;
  if (e >= ETOT) return;
  const int* ei; int E, loc, offd, rnoff, rel;
  if (e < 300000)      { ei = e0; E = 300000; loc = e;          offd = 0;     rnoff = 0;      rel = 0; }
  else if (e < 450000) { ei = e1; E = 150000; loc = e - 300000; offd = 50000; rnoff = 50000;  rel = 1; }
  else if (e < 550000) { ei = e2; E = 100000; loc = e - 450000; offd = 0;     rnoff = 100000; rel = 2; }
  else                 { ei = e3; E = 50000;  loc = e - 550000; offd = 50000; rnoff = 110000; rel = 3; }
  int src = ei[loc], dst = ei[E + loc];
  int dstg = offd + dst;
  int pos = atomicAdd(&cnt[dstg], 1);
  if (pos < SLOTS) elist[dstg*SLOTS + pos] = ((rnoff + src) << 2) | rel;
}

// ---------------- MFMA GEMM: block tile 64x128, wave tile 16x128 ----------------
// BT tile (128 n-rows x 128 k, bf16 = 32KB) staged in LDS, XOR-swizzled.

__device__ __forceinline__ void stage_bt(const u16* __restrict__ src, u16* BTl){
  int tid = threadIdx.x;
  const uint4* g = (const uint4*)src;          // 2048 uint4 = 32KB
  uint4 tmp[8];
#pragma unroll
  for (int i = 0; i < 8; i++) tmp[i] = g[tid + i*256];
#pragma unroll
  for (int i = 0; i < 8; i++){
    int L = (tid + i*256) * 16;                // linear byte in tile
    int Ls = L ^ (((L >> 8) & 7) << 4);        // swizzle: row bits 8-10 -> bits 4-6
    *(uint4*)((char*)BTl + Ls) = tmp[i];
  }
  __syncthreads();
}

__device__ __forceinline__ void gemm_core16(
    const u16* __restrict__ A, const u16* BTl, int M, int bm,
    f32x4 acc[8])
{
  int tid = threadIdx.x;
  int lane = tid & 63, w = tid >> 6;
  int quad = lane >> 4, lm = lane & 15;
  int row = bm + w*16 + lm;
  short8 af[4];
  if (row < M){
    const u16* ap = A + (size_t)row*128 + quad*8;
#pragma unroll
    for (int c = 0; c < 4; c++) af[c] = *(const short8*)(ap + c*32);
  } else {
    short8 z = {0,0,0,0,0,0,0,0};
#pragma unroll
    for (int c = 0; c < 4; c++) af[c] = z;
  }
#pragma unroll
  for (int nt = 0; nt < 8; nt++) acc[nt] = (f32x4){0.f,0.f,0.f,0.f};
#pragma unroll
  for (int nt = 0; nt < 8; nt++){
    int rowb = nt*16 + lm;
    int base = rowb*256 + quad*16;
    int sw = (rowb & 7) << 4;
#pragma unroll
    for (int c = 0; c < 4; c++){
      short8 bf = *(const short8*)((const char*)BTl + ((base + c*64) ^ sw));
      acc[nt] = __builtin_amdgcn_mfma_f32_16x16x32_bf16(af[c], bf, acc[nt], 0, 0, 0);
    }
  }
}

// Fused q+kv GEMM, one dispatch. 64-row tiles.
__global__ __launch_bounds__(256) void mfma_gemm_qkv(
    const u16* __restrict__ Xbf,
    const u16* __restrict__ WqTl, const float* __restrict__ bl,
    const u16* __restrict__ WeffTl, const float* __restrict__ beffl,
    u16* __restrict__ qg, u16* __restrict__ kv)
{
  __shared__ u16 BTl[16384];
  int by = blockIdx.x;
  const u16* A; const u16* BT; const float* bias;
  u16* C; int ldc, bm, M, bn;
  if (by < 1252){
    int t, roff;
    if (by < 782)       { t = 0; bm = by*64;         M = 50000; roff = 0; }
    else if (by < 1095) { t = 1; bm = (by-782)*64;   M = 20000; roff = 50000; }
    else                { t = 2; bm = (by-1095)*64;  M = 10000; roff = 70000; }
    A = Xbf + (size_t)roff*128;
    BT = WqTl + (size_t)t*16384;
    bias = bl + (size_t)t*384 + 128;
    C = qg + (size_t)roff*128; ldc = 128; bn = 0;
  } else {
    int idx = by - 1252;
    bn = (idx < 1878) ? 0 : 128;
    int tile = (idx < 1878) ? idx : idx - 1878;
    int r, soff, ooff;
    if (tile < 782)       { r = 0; bm = tile*64;        M = 50000; soff = 0;     ooff = 0; }
    else if (tile < 1564) { r = 1; bm = (tile-782)*64;  M = 50000; soff = 0;     ooff = 50000; }
    else if (tile < 1721) { r = 2; bm = (tile-1564)*64; M = 10000; soff = 70000; ooff = 100000; }
    else                  { r = 3; bm = (tile-1721)*64; M = 10000; soff = 70000; ooff = 110000; }
    A = Xbf + (size_t)soff*128;
    BT = WeffTl + (size_t)r*32768 + (size_t)bn*128;
    bias = beffl + (size_t)r*256 + bn;
    C = kv + (size_t)ooff*256 + bn; ldc = 256;
  }
  stage_bt(BT, BTl);
  f32x4 acc[8];
  gemm_core16(A, BTl, M, bm, acc);
  int lane = threadIdx.x & 63, w = threadIdx.x >> 6;
  int quad = lane >> 4, lm = lane & 15;
#pragma unroll
  for (int nt = 0; nt < 8; nt++){
    int col = nt*16 + lm;
    float bb = bias[col];
#pragma unroll
    for (int i = 0; i < 4; i++){
      int r = bm + w*16 + quad*4 + i;
      if (r < M) C[(size_t)r*ldc + col] = f2bf(acc[nt][i] + bb);
    }
  }
}

// Fused out-GEMM: A = G(bf16), epilogue skip+relu+residual -> X(fp32) [+ Xbf].
__global__ __launch_bounds__(256) void mfma_gemm_out(
    const u16* __restrict__ Gall, const u16* __restrict__ WoutTl,
    const float* __restrict__ bl, const float* __restrict__ skipl,
    float* __restrict__ Xall, u16* __restrict__ Xbfall)   // Xbfall==nullptr: skip
{
  __shared__ u16 BTl[16384];
  int by = blockIdx.x;
  int t, bm, M, roff;
  if (by < 782)       { t = 0; bm = by*64;         M = 50000; roff = 0; }
  else if (by < 1095) { t = 1; bm = (by-782)*64;   M = 20000; roff = 50000; }
  else                { t = 2; bm = (by-1095)*64;  M = 10000; roff = 70000; }
  stage_bt(WoutTl + (size_t)t*16384, BTl);
  const u16* A = Gall + (size_t)roff*128;
  const float* bias = bl + (size_t)t*128;
  float* X = Xall + (size_t)roff*128;
  u16* Xb = Xbfall ? (Xbfall + (size_t)roff*128) : (u16*)0;
  f32x4 acc[8];
  gemm_core16(A, BTl, M, bm, acc);
  float a_s = 1.f / (1.f + expf(-skipl[t]));
  float b_s = 1.f - a_s;
  int lane = threadIdx.x & 63, w = threadIdx.x >> 6;
  int quad = lane >> 4, lm = lane & 15;
#pragma unroll
  for (int nt = 0; nt < 8; nt++){
    int col = nt*16 + lm;
    float bb = bias[col];
#pragma unroll
    for (int i = 0; i < 4; i++){
      int r = bm + w*16 + quad*4 + i;
      if (r < M){
        float* xp = X + (size_t)r*128 + col;
        float x = *xp;
        float o = acc[nt][i] + bb;
        float xn = fmaxf(a_s*o + b_s*x, 0.f) + x;
        *xp = xn;
        if (Xb) Xb[(size_t)r*128 + col] = f2bf(xn);
      }
    }
  }
}

// ---------------- attention: 16 threads per node (2 per head) ----------------

__global__ __launch_bounds__(256) void attn_kernel(
    u16* __restrict__ qg,                   // NTOT x 128 bf16: q in, gelu(out) out
    const u16* __restrict__ kv,             // NSRC x 256 bf16: [k | v]
    const float* __restrict__ prel,         // + l*32
    const int* __restrict__ cnt,
    const int* __restrict__ elist)          // padded: node*SLOTS
{
  int gid = blockIdx.x * 256 + threadIdx.x;
  int n = gid >> 4;                          // node
  if (n >= NTOT) return;
  int lane = threadIdx.x & 63;
  int sub = (lane >> 3) & 1;                 // edge-half
  int h = lane & 7;                          // head
  float sc0 = prel[0*8+h]*0.25f, sc1 = prel[1*8+h]*0.25f,
        sc2 = prel[2*8+h]*0.25f, sc3 = prel[3*8+h]*0.25f;
  float q[16];
  load16bf(qg + (size_t)n * 128 + h*16, q);
  float acc[16] = {};
  float dsum = 0.f;
  int start = n * SLOTS, c = cnt[n];
  if (c > SLOTS) c = SLOTS;

  auto edge = [&](int ev, uint4 ka, uint4 kb, uint4 va, uint4 vb){
    float ke[16], ve[16];
    unp4(ka, ke); unp4(kb, ke + 8);
    unp4(va, ve); unp4(vb, ve + 8);
    float a = 0.f;
#pragma unroll
    for (int d = 0; d < 16; d++) a += q[d] * ke[d];
    int r = ev & 3;
    float s = (r == 0) ? sc0 : (r == 1) ? sc1 : (r == 2) ? sc2 : sc3;
    float ex = expf(a * s);
    dsum += ex;
#pragma unroll
    for (int d = 0; d < 16; d++) acc[d] += ex * ve[d];
  };

  int idx = sub;                             // this sub-thread: indices sub, sub+2, ...
#pragma unroll 1
  for (; idx + 6 < c; idx += 8){             // batch of 4 edges (stride 2)
    int e0 = elist[start + idx + 0], e1 = elist[start + idx + 2],
        e2 = elist[start + idx + 4], e3 = elist[start + idx + 6];
    const u16* p0 = kv + (size_t)(e0 >> 2) * 256 + h*16;
    const u16* p1 = kv + (size_t)(e1 >> 2) * 256 + h*16;
    const u16* p2 = kv + (size_t)(e2 >> 2) * 256 + h*16;
    const u16* p3 = kv + (size_t)(e3 >> 2) * 256 + h*16;
    uint4 k0a = *(const uint4*)p0,         k0b = *(const uint4*)(p0 + 8);
    uint4 k1a = *(const uint4*)p1,         k1b = *(const uint4*)(p1 + 8);
    uint4 k2a = *(const uint4*)p2,         k2b = *(const uint4*)(p2 + 8);
    uint4 k3a = *(const uint4*)p3,         k3b = *(const uint4*)(p3 + 8);
    uint4 v0a = *(const uint4*)(p0 + 128), v0b = *(const uint4*)(p0 + 136);
    uint4 v1a = *(const uint4*)(p1 + 128), v1b = *(const uint4*)(p1 + 136);
    uint4 v2a = *(const uint4*)(p2 + 128), v2b = *(const uint4*)(p2 + 136);
    uint4 v3a = *(const uint4*)(p3 + 128), v3b = *(const uint4*)(p3 + 136);
    edge(e0, k0a, k0b, v0a, v0b);
    edge(e1, k1a, k1b, v1a, v1b);
    edge(e2, k2a, k2b, v2a, v2b);
    edge(e3, k3a, k3b, v3a, v3b);
  }
#pragma unroll 1
  for (; idx < c; idx += 2){
    int ev = elist[start + idx];
    const u16* p = kv + (size_t)(ev >> 2) * 256 + h*16;
    uint4 ka = *(const uint4*)p,         kb = *(const uint4*)(p + 8);
    uint4 va = *(const uint4*)(p + 128), vb = *(const uint4*)(p + 136);
    edge(ev, ka, kb, va, vb);
  }

  // merge the two edge-halves (lane ^ 8 = same node, same head, other sub)
  dsum += __shfl_xor(dsum, 8);
#pragma unroll
  for (int d = 0; d < 16; d++) acc[d] += __shfl_xor(acc[d], 8);

  if (sub == 0){
    float inv = (c > 0) ? 1.f / dsum : 0.f;
    u16 o[16];
#pragma unroll
    for (int d = 0; d < 16; d++){
      float x = acc[d] * inv;
      o[d] = f2bf(0.5f * x * (1.f + erff(x * 0.70710678118654752f)));
    }
    uint4 p0, p1;
    p0.x = o[0]|(o[1]<<16);   p0.y = o[2]|(o[3]<<16);
    p0.z = o[4]|(o[5]<<16);   p0.w = o[6]|(o[7]<<16);
    p1.x = o[8]|(o[9]<<16);   p1.y = o[10]|(o[11]<<16);
    p1.z = o[12]|(o[13]<<16); p1.w = o[14]|(o[15]<<16);
    u16* op = qg + (size_t)n * 128 + h*16;
    *(uint4*)op = p0; *(uint4*)(op + 8) = p1;
  }
}

// ---------------- host ----------------

extern "C" void kernel_launch(void* const* d_in, const int* in_sizes, int n_in,
                              void* d_out, int out_size, void* d_ws, size_t ws_size,
                              hipStream_t stream)
{
  const float* xg   = (const float*)d_in[0];
  const float* xd   = (const float*)d_in[1];
  const float* xr_  = (const float*)d_in[2];
  const float* Wkqv = (const float*)d_in[3];
  const float* bkqv = (const float*)d_in[4];
  const float* Ak   = (const float*)d_in[5];
  const float* Av   = (const float*)d_in[6];
  const float* prel = (const float*)d_in[7];
  const float* Wout = (const float*)d_in[8];
  const float* bout = (const float*)d_in[9];
  const float* skip = (const float*)d_in[10];
  const int* ei[4] = {(const int*)d_in[11], (const int*)d_in[12],
                      (const int*)d_in[13], (const int*)d_in[14]};

  float* X = (float*)d_out;

  char* p = (char*)d_ws;
  auto alloc = [&](size_t b)->void*{ void* r = (void*)p; p += (b + 255) & ~(size_t)255; return r; };
  int*   cnt   = (int*)  alloc((size_t)NTOT * 4);
  int*   elist = (int*)  alloc((size_t)NTOT * SLOTS * 4);  // 41 MB padded
  float* beff  = (float*)alloc((size_t)8 * 256 * 4);
  u16*   qg    = (u16*)  alloc((size_t)NTOT * 128 * 2);    // 20.5 MB bf16
  u16*   kv    = (u16*)  alloc((size_t)NSRC * 256 * 2);    // 61.4 MB bf16
  u16*   Xbf   = (u16*)  alloc((size_t)NTOT * 128 * 2);    // 20.5 MB bf16
  u16*   WqT   = (u16*)  alloc((size_t)6 * 16384 * 2);
  u16*   WeffT = (u16*)  alloc((size_t)8 * 32768 * 2);
  u16*   WoutT = (u16*)  alloc((size_t)6 * 16384 * 2);
  (void)ws_size; (void)in_sizes; (void)n_in; (void)out_size;

  prep_all<<<(PR4 + 255)/256, 256, 0, stream>>>(
      xg, xd, xr_, X, Xbf, cnt,
      Wkqv, bkqv, Ak, Av, Wout, WeffT, WqT, WoutT, beff);

  scatter_direct<<<(ETOT+255)/256, 256, 0, stream>>>(
      ei[0], ei[1], ei[2], ei[3], cnt, elist);

  for (int l = 0; l < 2; l++){
    mfma_gemm_qkv<<<1252 + 3756, 256, 0, stream>>>(
        Xbf,
        WqT + (size_t)l*3*16384, bkqv + (size_t)l*3*384,
        WeffT + (size_t)l*4*32768, beff + (size_t)l*4*256,
        qg, kv);
    attn_kernel<<<5000, 256, 0, stream>>>(qg, kv, prel + l*32, cnt, elist);
    mfma_gemm_out<<<1252, 256, 0, stream>>>(
        qg, WoutT + (size_t)l*3*16384, bout + (size_t)l*3*128, skip + l*3,
        X, (l == 0) ? Xbf : (u16*)0);
  }
}

// Round 7
// 409.573 us; speedup vs baseline: 1.5175x; 1.0276x over previous
//
#include <hip/hip_runtime.h>

// HGT encoder, MI355X — ROUND 15.
// R14 post-mortem: attn ~55us (frozen, latency-bound at 40% HBM -> 60% of BW
// idle). Non-attn = ~311us over 6 dispatches; GEMMs ~2-3x their traffic
// floors; ~7us/dispatch launch gap (R13->R14 measured).
// R15: fuse out-GEMM INTO attn (attn_out): the out-GEMM's streaming X/W
// traffic hides under attn's idle bandwidth; kills the qg gelu round-trip
// (41MB/layer) and 2 dispatches. Block=256: 16 attn nodes + 16x128 out-tile
// (50000/20000/10000 all %16==0 -> no guards). stage WoutT(32KB LDS) -> attn
// -> gelu to swizzled 4KB G-LDS -> barrier -> 32 MFMA -> X epilogue.
// LDS 36KB -> 4 blocks/CU. cnt zero via hipMemsetAsync; scatter merged into
// prep_all. Dispatches 8 -> 6. Numerics bit-identical.
// MFMA layouts (guide-verified): A[m=lane&15][k=quad*8+j],
// B[k=quad*8+j][n=lane&15], D[row=quad*4+reg][col=lane&15].

#define NTOT  80000
#define ETOT  600000
#define NSRC  120000
#define SLOTS 128

typedef unsigned short u16;
typedef unsigned int   u32;
typedef __attribute__((ext_vector_type(8))) short short8;
typedef __attribute__((ext_vector_type(4))) float f32x4;

__device__ __forceinline__ u16 f2bf(float f){
  union { float f; u32 i; } v; v.f = f;
  u32 x = v.i;
  return (u16)((x + 0x7fffu + ((x >> 16) & 1u)) >> 16);   // RNE
}
__device__ __forceinline__ void unp4(uint4 a, float* o){
  union { u32 i; float f; } t;
  t.i = a.x << 16;        o[0]=t.f;  t.i = a.x & 0xffff0000u; o[1]=t.f;
  t.i = a.y << 16;        o[2]=t.f;  t.i = a.y & 0xffff0000u; o[3]=t.f;
  t.i = a.z << 16;        o[4]=t.f;  t.i = a.z & 0xffff0000u; o[5]=t.f;
  t.i = a.w << 16;        o[6]=t.f;  t.i = a.w & 0xffff0000u; o[7]=t.f;
}
__device__ __forceinline__ void load16bf(const u16* p, float* o){
  unp4(*(const uint4*)p, o); unp4(*(const uint4*)(p + 8), o + 8);
}

// ---------------- mega prep: X/Xbf + WeffT + WqT/WoutT + beff + scatter ----------------
// cnt must be zeroed (hipMemsetAsync) before this kernel.

#define PR0 2560000
#define PR1 (PR0 + 8*32768)
#define PR2 (PR1 + 2*6*16384)
#define PR3 (PR2 + 2048)
#define PR4 (PR3 + ETOT)

__global__ __launch_bounds__(256) void prep_all(
    const float* __restrict__ xg, const float* __restrict__ xd,
    const float* __restrict__ xr, float* __restrict__ X, u16* __restrict__ Xbf,
    const float* __restrict__ Wkqv, const float* __restrict__ bkqv,
    const float* __restrict__ Ak, const float* __restrict__ Av,
    const float* __restrict__ Wout,
    u16* __restrict__ WeffT, u16* __restrict__ WqT, u16* __restrict__ WoutT,
    float* __restrict__ beff,
    const int* __restrict__ e0, const int* __restrict__ e1,
    const int* __restrict__ e2, const int* __restrict__ e3,
    int* __restrict__ cnt, int* __restrict__ elist)
{
  int i = blockIdx.x * 256 + threadIdx.x;
  if (i < PR0){
    const float* src; int off;
    if (i < 1600000)      { src = xg; off = i; }
    else if (i < 2240000) { src = xd; off = i - 1600000; }
    else                  { src = xr; off = i - 2240000; }
    float4 v = ((const float4*)src)[off];
    ((float4*)X)[i] = v;
    uint2 b;
    b.x = (u32)f2bf(v.x) | ((u32)f2bf(v.y) << 16);
    b.y = (u32)f2bf(v.z) | ((u32)f2bf(v.w) << 16);
    ((uint2*)Xbf)[i] = b;
    return;
  }
  if (i < PR1){
    int j = i - PR0;
    int lr = j >> 15, rem = j & 32767, n = rem >> 7, k = rem & 127;
    int l = lr >> 2, r = lr & 3;
    int st = (r >= 2) ? 2 : 0;
    const float* W = Wkqv + (size_t)(l*3 + st) * 49152;
    float acc = 0.f;
    if (n < 128){
      int h = n >> 4, e = n & 15;
      const float* Am = Ak + (size_t)(l*4 + r) * 2048 + h*256;
#pragma unroll
      for (int d = 0; d < 16; d++) acc += W[k*384 + h*16 + d] * Am[d*16 + e];
    } else {
      int n2 = n - 128, h = n2 >> 4, e = n2 & 15;
      const float* Am = Av + (size_t)(l*4 + r) * 2048 + h*256;
#pragma unroll
      for (int d = 0; d < 16; d++) acc += W[k*384 + 256 + h*16 + d] * Am[d*16 + e];
    }
    WeffT[j] = f2bf(acc);
    return;
  }
  if (i < PR2){
    int j = i - PR1;
    if (j < 6*16384){
      int lt = j >> 14, rem = j & 16383, n = rem >> 7, k = rem & 127;
      WqT[j] = f2bf(Wkqv[(size_t)lt*49152 + k*384 + 128 + n]);
    } else {
      int j2 = j - 6*16384;
      int lt = j2 >> 14, rem = j2 & 16383, n = rem >> 7, k = rem & 127;
      WoutT[j2] = f2bf(Wout[(size_t)lt*16384 + k*128 + n]);
    }
    return;
  }
  if (i < PR3){
    int m = i - PR2;
    int lr = m >> 8, jj = m & 255;
    int l = lr >> 2, r = lr & 3;
    int st = (r >= 2) ? 2 : 0;
    const float* b = bkqv + (size_t)(l*3 + st) * 384;
    float acc = 0.f;
    if (jj < 128){
      int h = jj >> 4, e = jj & 15;
      const float* Am = Ak + (size_t)(l*4 + r) * 2048 + h*256;
#pragma unroll
      for (int d = 0; d < 16; d++) acc += b[h*16 + d] * Am[d*16 + e];
    } else {
      int j2 = jj - 128, h = j2 >> 4, e = j2 & 15;
      const float* Am = Av + (size_t)(l*4 + r) * 2048 + h*256;
#pragma unroll
      for (int d = 0; d < 16; d++) acc += b[256 + h*16 + d] * Am[d*16 + e];
    }
    beff[lr * 256 + jj] = acc;
    return;
  }
  if (i < PR4){
    int e = i - PR3;
    const int* ei; int E, loc, offd, rnoff, rel;
    if (e < 300000)      { ei = e0; E = 300000; loc = e;          offd = 0;     rnoff = 0;      rel = 0; }
    else if (e < 450000) { ei = e1; E = 150000; loc = e - 300000; offd = 50000; rnoff = 50000;  rel = 1; }
    else if (e < 550000) { ei = e2; E = 100000; loc = e - 450000; offd = 0;     rnoff = 100000; rel = 2; }
    else                 { ei = e3; E = 50000;  loc = e - 550000; offd = 50000; rnoff = 110000; rel = 3; }
    int src = ei[loc], dst = ei[E + loc];
    int dstg = offd + dst;
    int pos = atomicAdd(&cnt[dstg], 1);
    if (pos < SLOTS) elist[dstg*SLOTS + pos] = ((rnoff + src) << 2) | rel;
  }
}

// ---------------- MFMA GEMM: block tile 64x128, wave tile 16x128 (qkv) ----------------

__device__ __forceinline__ void stage_bt(const u16* __restrict__ src, u16* BTl){
  int tid = threadIdx.x;
  const uint4* g = (const uint4*)src;          // 2048 uint4 = 32KB
  uint4 tmp[8];
#pragma unroll
  for (int i = 0; i < 8; i++) tmp[i] = g[tid + i*256];
#pragma unroll
  for (int i = 0; i < 8; i++){
    int L = (tid + i*256) * 16;                // linear byte in tile
    int Ls = L ^ (((L >> 8) & 7) << 4);        // swizzle: row bits 8-10 -> bits 4-6
    *(uint4*)((char*)BTl + Ls) = tmp[i];
  }
}

__device__ __forceinline__ void gemm_core16(
    const u16* __restrict__ A, const u16* BTl, int M, int bm,
    f32x4 acc[8])
{
  int tid = threadIdx.x;
  int lane = tid & 63, w = tid >> 6;
  int quad = lane >> 4, lm = lane & 15;
  int row = bm + w*16 + lm;
  short8 af[4];
  if (row < M){
    const u16* ap = A + (size_t)row*128 + quad*8;
#pragma unroll
    for (int c = 0; c < 4; c++) af[c] = *(const short8*)(ap + c*32);
  } else {
    short8 z = {0,0,0,0,0,0,0,0};
#pragma unroll
    for (int c = 0; c < 4; c++) af[c] = z;
  }
#pragma unroll
  for (int nt = 0; nt < 8; nt++) acc[nt] = (f32x4){0.f,0.f,0.f,0.f};
#pragma unroll
  for (int nt = 0; nt < 8; nt++){
    int rowb = nt*16 + lm;
    int base = rowb*256 + quad*16;
    int sw = (rowb & 7) << 4;
#pragma unroll
    for (int c = 0; c < 4; c++){
      short8 bf = *(const short8*)((const char*)BTl + ((base + c*64) ^ sw));
      acc[nt] = __builtin_amdgcn_mfma_f32_16x16x32_bf16(af[c], bf, acc[nt], 0, 0, 0);
    }
  }
}

// Fused q+kv GEMM, one dispatch. 64-row tiles.
__global__ __launch_bounds__(256) void mfma_gemm_qkv(
    const u16* __restrict__ Xbf,
    const u16* __restrict__ WqTl, const float* __restrict__ bl,
    const u16* __restrict__ WeffTl, const float* __restrict__ beffl,
    u16* __restrict__ qg, u16* __restrict__ kv)
{
  __shared__ u16 BTl[16384];
  int by = blockIdx.x;
  const u16* A; const u16* BT; const float* bias;
  u16* C; int ldc, bm, M, bn;
  if (by < 1252){
    int t, roff;
    if (by < 782)       { t = 0; bm = by*64;         M = 50000; roff = 0; }
    else if (by < 1095) { t = 1; bm = (by-782)*64;   M = 20000; roff = 50000; }
    else                { t = 2; bm = (by-1095)*64;  M = 10000; roff = 70000; }
    A = Xbf + (size_t)roff*128;
    BT = WqTl + (size_t)t*16384;
    bias = bl + (size_t)t*384 + 128;
    C = qg + (size_t)roff*128; ldc = 128; bn = 0;
  } else {
    int idx = by - 1252;
    bn = (idx < 1878) ? 0 : 128;
    int tile = (idx < 1878) ? idx : idx - 1878;
    int r, soff, ooff;
    if (tile < 782)       { r = 0; bm = tile*64;        M = 50000; soff = 0;     ooff = 0; }
    else if (tile < 1564) { r = 1; bm = (tile-782)*64;  M = 50000; soff = 0;     ooff = 50000; }
    else if (tile < 1721) { r = 2; bm = (tile-1564)*64; M = 10000; soff = 70000; ooff = 100000; }
    else                  { r = 3; bm = (tile-1721)*64; M = 10000; soff = 70000; ooff = 110000; }
    A = Xbf + (size_t)soff*128;
    BT = WeffTl + (size_t)r*32768 + (size_t)bn*128;
    bias = beffl + (size_t)r*256 + bn;
    C = kv + (size_t)ooff*256 + bn; ldc = 256;
  }
  stage_bt(BT, BTl);
  __syncthreads();
  f32x4 acc[8];
  gemm_core16(A, BTl, M, bm, acc);
  int lane = threadIdx.x & 63, w = threadIdx.x >> 6;
  int quad = lane >> 4, lm = lane & 15;
#pragma unroll
  for (int nt = 0; nt < 8; nt++){
    int col = nt*16 + lm;
    float bb = bias[col];
#pragma unroll
    for (int i = 0; i < 4; i++){
      int r = bm + w*16 + quad*4 + i;
      if (r < M) C[(size_t)r*ldc + col] = f2bf(acc[nt][i] + bb);
    }
  }
}

// ---------------- fused attention + out-GEMM ----------------
// Block = 256 threads: 16 nodes attn (16 thr/node) + 16x128 out-GEMM tile.
// 50000/20000/10000 all %16 == 0 -> tiles never straddle types, no row guards.
// Grid 5000: t0 [0,3125) t1 [3125,4375) t2 [4375,5000).

__global__ __launch_bounds__(256) void attn_out(
    const u16* __restrict__ qg,             // NTOT x 128 bf16: q
    const u16* __restrict__ kv,             // NSRC x 256 bf16: [k | v]
    const float* __restrict__ prel,         // + l*32
    const int* __restrict__ cnt,
    const int* __restrict__ elist,          // padded: node*SLOTS
    const u16* __restrict__ WoutTl,         // + t*16384
    const float* __restrict__ bl,           // + t*128
    const float* __restrict__ skipl,        // + t
    float* __restrict__ Xall, u16* __restrict__ Xbfall)  // Xbfall null -> skip
{
  __shared__ u16 BT[16384];                 // 32KB WoutT tile (swizzled)
  __shared__ u16 G[2048];                   // 4KB gelu-out tile 16x128 (swizzled)
  int bid = blockIdx.x;
  int t, bm, roff;
  if (bid < 3125)      { t = 0; bm = bid*16;        roff = 0; }
  else if (bid < 4375) { t = 1; bm = (bid-3125)*16; roff = 50000; }
  else                 { t = 2; bm = (bid-4375)*16; roff = 70000; }

  stage_bt(WoutTl + (size_t)t*16384, BT);   // writes ordered by the barrier below

  // ---- attention phase (R12 structure, 16 thr/node) ----
  int tid = threadIdx.x;
  int slot = tid >> 4;                      // 0..15
  int n = roff + bm + slot;
  int lane = tid & 63;
  int sub = (lane >> 3) & 1;
  int h = lane & 7;
  float sc0 = prel[0*8+h]*0.25f, sc1 = prel[1*8+h]*0.25f,
        sc2 = prel[2*8+h]*0.25f, sc3 = prel[3*8+h]*0.25f;
  float q[16];
  load16bf(qg + (size_t)n * 128 + h*16, q);
  float acc[16] = {};
  float dsum = 0.f;
  int start = n * SLOTS, c = cnt[n];
  if (c > SLOTS) c = SLOTS;

  auto edge = [&](int ev, uint4 ka, uint4 kb, uint4 va, uint4 vb){
    float ke[16], ve[16];
    unp4(ka, ke); unp4(kb, ke + 8);
    unp4(va, ve); unp4(vb, ve + 8);
    float a = 0.f;
#pragma unroll
    for (int d = 0; d < 16; d++) a += q[d] * ke[d];
    int r = ev & 3;
    float s = (r == 0) ? sc0 : (r == 1) ? sc1 : (r == 2) ? sc2 : sc3;
    float ex = expf(a * s);
    dsum += ex;
#pragma unroll
    for (int d = 0; d < 16; d++) acc[d] += ex * ve[d];
  };

  int idx = sub;
#pragma unroll 1
  for (; idx + 6 < c; idx += 8){
    int e0 = elist[start + idx + 0], e1 = elist[start + idx + 2],
        e2 = elist[start + idx + 4], e3 = elist[start + idx + 6];
    const u16* p0 = kv + (size_t)(e0 >> 2) * 256 + h*16;
    const u16* p1 = kv + (size_t)(e1 >> 2) * 256 + h*16;
    const u16* p2 = kv + (size_t)(e2 >> 2) * 256 + h*16;
    const u16* p3 = kv + (size_t)(e3 >> 2) * 256 + h*16;
    uint4 k0a = *(const uint4*)p0,         k0b = *(const uint4*)(p0 + 8);
    uint4 k1a = *(const uint4*)p1,         k1b = *(const uint4*)(p1 + 8);
    uint4 k2a = *(const uint4*)p2,         k2b = *(const uint4*)(p2 + 8);
    uint4 k3a = *(const uint4*)p3,         k3b = *(const uint4*)(p3 + 8);
    uint4 v0a = *(const uint4*)(p0 + 128), v0b = *(const uint4*)(p0 + 136);
    uint4 v1a = *(const uint4*)(p1 + 128), v1b = *(const uint4*)(p1 + 136);
    uint4 v2a = *(const uint4*)(p2 + 128), v2b = *(const uint4*)(p2 + 136);
    uint4 v3a = *(const uint4*)(p3 + 128), v3b = *(const uint4*)(p3 + 136);
    edge(e0, k0a, k0b, v0a, v0b);
    edge(e1, k1a, k1b, v1a, v1b);
    edge(e2, k2a, k2b, v2a, v2b);
    edge(e3, k3a, k3b, v3a, v3b);
  }
#pragma unroll 1
  for (; idx < c; idx += 2){
    int ev = elist[start + idx];
    const u16* p = kv + (size_t)(ev >> 2) * 256 + h*16;
    uint4 ka = *(const uint4*)p,         kb = *(const uint4*)(p + 8);
    uint4 va = *(const uint4*)(p + 128), vb = *(const uint4*)(p + 136);
    edge(ev, ka, kb, va, vb);
  }

  dsum += __shfl_xor(dsum, 8);
#pragma unroll
  for (int d = 0; d < 16; d++) acc[d] += __shfl_xor(acc[d], 8);

  if (sub == 0){
    float inv = (c > 0) ? 1.f / dsum : 0.f;
    u16 o[16];
#pragma unroll
    for (int d = 0; d < 16; d++){
      float x = acc[d] * inv;
      o[d] = f2bf(0.5f * x * (1.f + erff(x * 0.70710678118654752f)));
    }
    uint4 p0, p1;
    p0.x = o[0]|(o[1]<<16);   p0.y = o[2]|(o[3]<<16);
    p0.z = o[4]|(o[5]<<16);   p0.w = o[6]|(o[7]<<16);
    p1.x = o[8]|(o[9]<<16);   p1.y = o[10]|(o[11]<<16);
    p1.z = o[12]|(o[13]<<16); p1.w = o[14]|(o[15]<<16);
    int b0 = slot*256 + h*32;
    int sw = (slot & 7) << 4;
    *(uint4*)((char*)G + (b0 ^ sw))        = p0;
    *(uint4*)((char*)G + ((b0 + 16) ^ sw)) = p1;
  }
  __syncthreads();   // G + BT visible

  // ---- out-GEMM phase: 16x128 tile, wave w -> cols [w*32, w*32+32) ----
  int w = tid >> 6;
  int quad = lane >> 4, lm = lane & 15;
  short8 af[4];
  {
    int base = lm*256 + quad*16;
    int sw = (lm & 7) << 4;
#pragma unroll
    for (int c2 = 0; c2 < 4; c2++)
      af[c2] = *(const short8*)((const char*)G + ((base + c2*64) ^ sw));
  }
  f32x4 oacc[2];
#pragma unroll
  for (int nt = 0; nt < 2; nt++){
    oacc[nt] = (f32x4){0.f,0.f,0.f,0.f};
    int rowb = w*32 + nt*16 + lm;
    int base = rowb*256 + quad*16;
    int sw = (rowb & 7) << 4;
#pragma unroll
    for (int c2 = 0; c2 < 4; c2++){
      short8 bf = *(const short8*)((const char*)BT + ((base + c2*64) ^ sw));
      oacc[nt] = __builtin_amdgcn_mfma_f32_16x16x32_bf16(af[c2], bf, oacc[nt], 0, 0, 0);
    }
  }
  float a_s = 1.f / (1.f + expf(-skipl[t]));
  float b_s = 1.f - a_s;
  const float* bias = bl + (size_t)t*128;
  float* X = Xall + (size_t)roff*128;
  u16* Xb = Xbfall ? (Xbfall + (size_t)roff*128) : (u16*)0;
#pragma unroll
  for (int nt = 0; nt < 2; nt++){
    int col = w*32 + nt*16 + lm;
    float bb = bias[col];
#pragma unroll
    for (int i = 0; i < 4; i++){
      int r = bm + quad*4 + i;
      float* xp = X + (size_t)r*128 + col;
      float x = *xp;
      float o = oacc[nt][i] + bb;
      float xn = fmaxf(a_s*o + b_s*x, 0.f) + x;
      *xp = xn;
      if (Xb) Xb[(size_t)r*128 + col] = f2bf(xn);
    }
  }
}

// ---------------- host ----------------

extern "C" void kernel_launch(void* const* d_in, const int* in_sizes, int n_in,
                              void* d_out, int out_size, void* d_ws, size_t ws_size,
                              hipStream_t stream)
{
  const float* xg   = (const float*)d_in[0];
  const float* xd   = (const float*)d_in[1];
  const float* xr_  = (const float*)d_in[2];
  const float* Wkqv = (const float*)d_in[3];
  const float* bkqv = (const float*)d_in[4];
  const float* Ak   = (const float*)d_in[5];
  const float* Av   = (const float*)d_in[6];
  const float* prel = (const float*)d_in[7];
  const float* Wout = (const float*)d_in[8];
  const float* bout = (const float*)d_in[9];
  const float* skip = (const float*)d_in[10];
  const int* ei[4] = {(const int*)d_in[11], (const int*)d_in[12],
                      (const int*)d_in[13], (const int*)d_in[14]};

  float* X = (float*)d_out;

  char* p = (char*)d_ws;
  auto alloc = [&](size_t b)->void*{ void* r = (void*)p; p += (b + 255) & ~(size_t)255; return r; };
  int*   cnt   = (int*)  alloc((size_t)NTOT * 4);
  int*   elist = (int*)  alloc((size_t)NTOT * SLOTS * 4);  // 41 MB padded
  float* beff  = (float*)alloc((size_t)8 * 256 * 4);
  u16*   qg    = (u16*)  alloc((size_t)NTOT * 128 * 2);    // 20.5 MB bf16
  u16*   kv    = (u16*)  alloc((size_t)NSRC * 256 * 2);    // 61.4 MB bf16
  u16*   Xbf   = (u16*)  alloc((size_t)NTOT * 128 * 2);    // 20.5 MB bf16
  u16*   WqT   = (u16*)  alloc((size_t)6 * 16384 * 2);
  u16*   WeffT = (u16*)  alloc((size_t)8 * 32768 * 2);
  u16*   WoutT = (u16*)  alloc((size_t)6 * 16384 * 2);
  (void)ws_size; (void)in_sizes; (void)n_in; (void)out_size;

  hipMemsetAsync(cnt, 0, (size_t)NTOT * 4, stream);

  prep_all<<<(PR4 + 255)/256, 256, 0, stream>>>(
      xg, xd, xr_, X, Xbf,
      Wkqv, bkqv, Ak, Av, Wout, WeffT, WqT, WoutT, beff,
      ei[0], ei[1], ei[2], ei[3], cnt, elist);

  for (int l = 0; l < 2; l++){
    mfma_gemm_qkv<<<1252 + 3756, 256, 0, stream>>>(
        Xbf,
        WqT + (size_t)l*3*16384, bkqv + (size_t)l*3*384,
        WeffT + (size_t)l*4*32768, beff + (size_t)l*4*256,
        qg, kv);
    attn_out<<<5000, 256, 0, stream>>>(
        qg, kv, prel + l*32, cnt, elist,
        WoutT + (size_t)l*3*16384, bout + (size_t)l*3*128, skip + l*3,
        X, (l == 0) ? Xbf : (u16*)0);
  }
}

// Round 9
// 396.436 us; speedup vs baseline: 1.5678x; 1.0331x over previous
//
#include <hip/hip_runtime.h>

// HGT encoder, MI355X — ROUND 17 (= R16 resubmit; container infra failure,
// kernel never executed).
// R15 post-mortem: attn_out occupancy 30% — 32KB WoutT LDS tile caps
// residency at 4 blocks/CU; the GEMM phase only needs 8 B-frags/thread from
// an L2-hot 32KB table.
// Changes vs R15:
//  1. attn_out: WoutT read per-thread from global (loads issued after attn
//     loop -> latency hides in barrier wait). LDS 36KB -> 4KB (G only).
//  2. qkv-GEMM: 1252 blocks load A-frags ONCE, loop over col-tiles
//     (gene/drug: q + 2 relations x 2 halves = 5; disease: 1). A-traffic
//     -60MB/layer; 5x MFMA per stage. Heavy blocks first.
// Numerics bit-identical (same f2bf points, same order).
// MFMA layouts (guide-verified): A[m=lane&15][k=quad*8+j],
// B[k=quad*8+j][n=lane&15], D[row=quad*4+reg][col=lane&15].

#define NTOT  80000
#define ETOT  600000
#define NSRC  120000
#define SLOTS 128

typedef unsigned short u16;
typedef unsigned int   u32;
typedef __attribute__((ext_vector_type(8))) short short8;
typedef __attribute__((ext_vector_type(4))) float f32x4;

__device__ __forceinline__ u16 f2bf(float f){
  union { float f; u32 i; } v; v.f = f;
  u32 x = v.i;
  return (u16)((x + 0x7fffu + ((x >> 16) & 1u)) >> 16);   // RNE
}
__device__ __forceinline__ void unp4(uint4 a, float* o){
  union { u32 i; float f; } t;
  t.i = a.x << 16;        o[0]=t.f;  t.i = a.x & 0xffff0000u; o[1]=t.f;
  t.i = a.y << 16;        o[2]=t.f;  t.i = a.y & 0xffff0000u; o[3]=t.f;
  t.i = a.z << 16;        o[4]=t.f;  t.i = a.z & 0xffff0000u; o[5]=t.f;
  t.i = a.w << 16;        o[6]=t.f;  t.i = a.w & 0xffff0000u; o[7]=t.f;
}
__device__ __forceinline__ void load16bf(const u16* p, float* o){
  unp4(*(const uint4*)p, o); unp4(*(const uint4*)(p + 8), o + 8);
}

// ---------------- mega prep: X/Xbf + WeffT + WqT/WoutT + beff + scatter ----------------
// cnt must be zeroed (hipMemsetAsync) before this kernel.

#define PR0 2560000
#define PR1 (PR0 + 8*32768)
#define PR2 (PR1 + 2*6*16384)
#define PR3 (PR2 + 2048)
#define PR4 (PR3 + ETOT)

__global__ __launch_bounds__(256) void prep_all(
    const float* __restrict__ xg, const float* __restrict__ xd,
    const float* __restrict__ xr, float* __restrict__ X, u16* __restrict__ Xbf,
    const float* __restrict__ Wkqv, const float* __restrict__ bkqv,
    const float* __restrict__ Ak, const float* __restrict__ Av,
    const float* __restrict__ Wout,
    u16* __restrict__ WeffT, u16* __restrict__ WqT, u16* __restrict__ WoutT,
    float* __restrict__ beff,
    const int* __restrict__ e0, const int* __restrict__ e1,
    const int* __restrict__ e2, const int* __restrict__ e3,
    int* __restrict__ cnt, int* __restrict__ elist)
{
  int i = blockIdx.x * 256 + threadIdx.x;
  if (i < PR0){
    const float* src; int off;
    if (i < 1600000)      { src = xg; off = i; }
    else if (i < 2240000) { src = xd; off = i - 1600000; }
    else                  { src = xr; off = i - 2240000; }
    float4 v = ((const float4*)src)[off];
    ((float4*)X)[i] = v;
    uint2 b;
    b.x = (u32)f2bf(v.x) | ((u32)f2bf(v.y) << 16);
    b.y = (u32)f2bf(v.z) | ((u32)f2bf(v.w) << 16);
    ((uint2*)Xbf)[i] = b;
    return;
  }
  if (i < PR1){
    int j = i - PR0;
    int lr = j >> 15, rem = j & 32767, n = rem >> 7, k = rem & 127;
    int l = lr >> 2, r = lr & 3;
    int st = (r >= 2) ? 2 : 0;
    const float* W = Wkqv + (size_t)(l*3 + st) * 49152;
    float acc = 0.f;
    if (n < 128){
      int h = n >> 4, e = n & 15;
      const float* Am = Ak + (size_t)(l*4 + r) * 2048 + h*256;
#pragma unroll
      for (int d = 0; d < 16; d++) acc += W[k*384 + h*16 + d] * Am[d*16 + e];
    } else {
      int n2 = n - 128, h = n2 >> 4, e = n2 & 15;
      const float* Am = Av + (size_t)(l*4 + r) * 2048 + h*256;
#pragma unroll
      for (int d = 0; d < 16; d++) acc += W[k*384 + 256 + h*16 + d] * Am[d*16 + e];
    }
    WeffT[j] = f2bf(acc);
    return;
  }
  if (i < PR2){
    int j = i - PR1;
    if (j < 6*16384){
      int lt = j >> 14, rem = j & 16383, n = rem >> 7, k = rem & 127;
      WqT[j] = f2bf(Wkqv[(size_t)lt*49152 + k*384 + 128 + n]);
    } else {
      int j2 = j - 6*16384;
      int lt = j2 >> 14, rem = j2 & 16383, n = rem >> 7, k = rem & 127;
      WoutT[j2] = f2bf(Wout[(size_t)lt*16384 + k*128 + n]);
    }
    return;
  }
  if (i < PR3){
    int m = i - PR2;
    int lr = m >> 8, jj = m & 255;
    int l = lr >> 2, r = lr & 3;
    int st = (r >= 2) ? 2 : 0;
    const float* b = bkqv + (size_t)(l*3 + st) * 384;
    float acc = 0.f;
    if (jj < 128){
      int h = jj >> 4, e = jj & 15;
      const float* Am = Ak + (size_t)(l*4 + r) * 2048 + h*256;
#pragma unroll
      for (int d = 0; d < 16; d++) acc += b[h*16 + d] * Am[d*16 + e];
    } else {
      int j2 = jj - 128, h = j2 >> 4, e = j2 & 15;
      const float* Am = Av + (size_t)(l*4 + r) * 2048 + h*256;
#pragma unroll
      for (int d = 0; d < 16; d++) acc += b[256 + h*16 + d] * Am[d*16 + e];
    }
    beff[lr * 256 + jj] = acc;
    return;
  }
  if (i < PR4){
    int e = i - PR3;
    const int* ei; int E, loc, offd, rnoff, rel;
    if (e < 300000)      { ei = e0; E = 300000; loc = e;          offd = 0;     rnoff = 0;      rel = 0; }
    else if (e < 450000) { ei = e1; E = 150000; loc = e - 300000; offd = 50000; rnoff = 50000;  rel = 1; }
    else if (e < 550000) { ei = e2; E = 100000; loc = e - 450000; offd = 0;     rnoff = 100000; rel = 2; }
    else                 { ei = e3; E = 50000;  loc = e - 550000; offd = 50000; rnoff = 110000; rel = 3; }
    int src = ei[loc], dst = ei[E + loc];
    int dstg = offd + dst;
    int pos = atomicAdd(&cnt[dstg], 1);
    if (pos < SLOTS) elist[dstg*SLOTS + pos] = ((rnoff + src) << 2) | rel;
  }
}

// ---------------- MFMA GEMM helpers ----------------

__device__ __forceinline__ void stage_bt(const u16* __restrict__ src, u16* BTl){
  int tid = threadIdx.x;
  const uint4* g = (const uint4*)src;          // 2048 uint4 = 32KB
  uint4 tmp[8];
#pragma unroll
  for (int i = 0; i < 8; i++) tmp[i] = g[tid + i*256];
#pragma unroll
  for (int i = 0; i < 8; i++){
    int L = (tid + i*256) * 16;                // linear byte in tile
    int Ls = L ^ (((L >> 8) & 7) << 4);        // swizzle: row bits 8-10 -> bits 4-6
    *(uint4*)((char*)BTl + Ls) = tmp[i];
  }
}

// one 64-row x 128-col output tile from pre-loaded A-frags
__device__ __forceinline__ void do_tile(
    const u16* __restrict__ BTsrc, const float* __restrict__ bias,
    u16* __restrict__ C, int ldc, int bm, int M, const short8 af[4], u16* BTl)
{
  stage_bt(BTsrc, BTl);
  __syncthreads();
  int tid = threadIdx.x;
  int lane = tid & 63, w = tid >> 6;
  int quad = lane >> 4, lm = lane & 15;
  f32x4 acc[8];
#pragma unroll
  for (int nt = 0; nt < 8; nt++) acc[nt] = (f32x4){0.f,0.f,0.f,0.f};
#pragma unroll
  for (int nt = 0; nt < 8; nt++){
    int rowb = nt*16 + lm;
    int base = rowb*256 + quad*16;
    int sw = (rowb & 7) << 4;
#pragma unroll
    for (int c = 0; c < 4; c++){
      short8 bf = *(const short8*)((const char*)BTl + ((base + c*64) ^ sw));
      acc[nt] = __builtin_amdgcn_mfma_f32_16x16x32_bf16(af[c], bf, acc[nt], 0, 0, 0);
    }
  }
  __syncthreads();
#pragma unroll
  for (int nt = 0; nt < 8; nt++){
    int col = nt*16 + lm;
    float bb = bias[col];
#pragma unroll
    for (int i = 0; i < 4; i++){
      int r = bm + w*16 + quad*4 + i;
      if (r < M) C[(size_t)r*ldc + col] = f2bf(acc[nt][i] + bb);
    }
  }
}

// Fused q+kv GEMM: A-frags loaded once, loop over col-tiles.
// by [0,782): gene t0 (5 tiles)  [782,939): drug t2 (5 tiles)
// [939,1252): disease t1 (1 tile)
__global__ __launch_bounds__(256) void mfma_gemm_qkv(
    const u16* __restrict__ Xbf,
    const u16* __restrict__ WqTl, const float* __restrict__ bl,
    const u16* __restrict__ WeffTl, const float* __restrict__ beffl,
    u16* __restrict__ qg, u16* __restrict__ kv)
{
  __shared__ u16 BTl[16384];
  int by = blockIdx.x;
  int t, bm, M, roff, rbase, o0, o1; bool haskv;
  if (by < 782)      { t = 0; bm = by*64;        M = 50000; roff = 0;     haskv = true;  rbase = 0; o0 = 0;      o1 = 50000; }
  else if (by < 939) { t = 2; bm = (by-782)*64;  M = 10000; roff = 70000; haskv = true;  rbase = 2; o0 = 100000; o1 = 110000; }
  else               { t = 1; bm = (by-939)*64;  M = 20000; roff = 50000; haskv = false; rbase = 0; o0 = 0;      o1 = 0; }

  int tid = threadIdx.x;
  int lane = tid & 63, w = tid >> 6;
  int quad = lane >> 4, lm = lane & 15;
  int row = bm + w*16 + lm;
  short8 af[4];
  if (row < M){
    const u16* ap = Xbf + (size_t)(roff + row)*128 + quad*8;
#pragma unroll
    for (int c = 0; c < 4; c++) af[c] = *(const short8*)(ap + c*32);
  } else {
    short8 z = {0,0,0,0,0,0,0,0};
#pragma unroll
    for (int c = 0; c < 4; c++) af[c] = z;
  }

  // q tile
  do_tile(WqTl + (size_t)t*16384, bl + (size_t)t*384 + 128,
          qg + (size_t)roff*128, 128, bm, M, af, BTl);
  // kv tiles
  if (haskv){
#pragma unroll 1
    for (int s = 0; s < 4; s++){
      int r  = rbase + (s >> 1);
      int bn = (s & 1) * 128;
      int oo = (s < 2) ? o0 : o1;
      do_tile(WeffTl + (size_t)r*32768 + (size_t)bn*128,
              beffl + (size_t)r*256 + bn,
              kv + (size_t)oo*256 + bn, 256, bm, M, af, BTl);
    }
  }
}

// ---------------- fused attention + out-GEMM (no B LDS) ----------------
// Block = 256: 16 nodes attn (16 thr/node) + 16x128 out-GEMM tile.
// Grid 5000: t0 [0,3125) t1 [3125,4375) t2 [4375,5000).

__global__ __launch_bounds__(256) void attn_out(
    const u16* __restrict__ qg,             // NTOT x 128 bf16: q
    const u16* __restrict__ kv,             // NSRC x 256 bf16: [k | v]
    const float* __restrict__ prel,         // + l*32
    const int* __restrict__ cnt,
    const int* __restrict__ elist,          // padded: node*SLOTS
    const u16* __restrict__ WoutTl,         // + t*16384
    const float* __restrict__ bl,           // + t*128
    const float* __restrict__ skipl,        // + t
    float* __restrict__ Xall, u16* __restrict__ Xbfall)  // Xbfall null -> skip
{
  __shared__ u16 G[2048];                   // 4KB gelu-out tile 16x128 (swizzled)
  int bid = blockIdx.x;
  int t, bm, roff;
  if (bid < 3125)      { t = 0; bm = bid*16;        roff = 0; }
  else if (bid < 4375) { t = 1; bm = (bid-3125)*16; roff = 50000; }
  else                 { t = 2; bm = (bid-4375)*16; roff = 70000; }

  // ---- attention phase (R12 structure, 16 thr/node) ----
  int tid = threadIdx.x;
  int slot = tid >> 4;                      // 0..15
  int n = roff + bm + slot;
  int lane = tid & 63;
  int sub = (lane >> 3) & 1;
  int h = lane & 7;
  float sc0 = prel[0*8+h]*0.25f, sc1 = prel[1*8+h]*0.25f,
        sc2 = prel[2*8+h]*0.25f, sc3 = prel[3*8+h]*0.25f;
  float q[16];
  load16bf(qg + (size_t)n * 128 + h*16, q);
  float acc[16] = {};
  float dsum = 0.f;
  int start = n * SLOTS, c = cnt[n];
  if (c > SLOTS) c = SLOTS;

  auto edge = [&](int ev, uint4 ka, uint4 kb, uint4 va, uint4 vb){
    float ke[16], ve[16];
    unp4(ka, ke); unp4(kb, ke + 8);
    unp4(va, ve); unp4(vb, ve + 8);
    float a = 0.f;
#pragma unroll
    for (int d = 0; d < 16; d++) a += q[d] * ke[d];
    int r = ev & 3;
    float s = (r == 0) ? sc0 : (r == 1) ? sc1 : (r == 2) ? sc2 : sc3;
    float ex = expf(a * s);
    dsum += ex;
#pragma unroll
    for (int d = 0; d < 16; d++) acc[d] += ex * ve[d];
  };

  int idx = sub;
#pragma unroll 1
  for (; idx + 6 < c; idx += 8){
    int e0 = elist[start + idx + 0], e1 = elist[start + idx + 2],
        e2 = elist[start + idx + 4], e3 = elist[start + idx + 6];
    const u16* p0 = kv + (size_t)(e0 >> 2) * 256 + h*16;
    const u16* p1 = kv + (size_t)(e1 >> 2) * 256 + h*16;
    const u16* p2 = kv + (size_t)(e2 >> 2) * 256 + h*16;
    const u16* p3 = kv + (size_t)(e3 >> 2) * 256 + h*16;
    uint4 k0a = *(const uint4*)p0,         k0b = *(const uint4*)(p0 + 8);
    uint4 k1a = *(const uint4*)p1,         k1b = *(const uint4*)(p1 + 8);
    uint4 k2a = *(const uint4*)p2,         k2b = *(const uint4*)(p2 + 8);
    uint4 k3a = *(const uint4*)p3,         k3b = *(const uint4*)(p3 + 8);
    uint4 v0a = *(const uint4*)(p0 + 128), v0b = *(const uint4*)(p0 + 136);
    uint4 v1a = *(const uint4*)(p1 + 128), v1b = *(const uint4*)(p1 + 136);
    uint4 v2a = *(const uint4*)(p2 + 128), v2b = *(const uint4*)(p2 + 136);
    uint4 v3a = *(const uint4*)(p3 + 128), v3b = *(const uint4*)(p3 + 136);
    edge(e0, k0a, k0b, v0a, v0b);
    edge(e1, k1a, k1b, v1a, v1b);
    edge(e2, k2a, k2b, v2a, v2b);
    edge(e3, k3a, k3b, v3a, v3b);
  }
#pragma unroll 1
  for (; idx < c; idx += 2){
    int ev = elist[start + idx];
    const u16* p = kv + (size_t)(ev >> 2) * 256 + h*16;
    uint4 ka = *(const uint4*)p,         kb = *(const uint4*)(p + 8);
    uint4 va = *(const uint4*)(p + 128), vb = *(const uint4*)(p + 136);
    edge(ev, ka, kb, va, vb);
  }

  // W-fragment loads (L2-hot, 128B/thread) — issued here so their latency
  // overlaps the pre-barrier wait while other waves still run attn.
  int w = tid >> 6;
  int quad = lane >> 4, lm = lane & 15;
  short8 wf[2][4];
  {
    const u16* wp = WoutTl + (size_t)t*16384;
#pragma unroll
    for (int nt = 0; nt < 2; nt++){
      const u16* wr = wp + (size_t)(w*32 + nt*16 + lm)*128 + quad*8;
#pragma unroll
      for (int c2 = 0; c2 < 4; c2++) wf[nt][c2] = *(const short8*)(wr + c2*32);
    }
  }

  dsum += __shfl_xor(dsum, 8);
#pragma unroll
  for (int d = 0; d < 16; d++) acc[d] += __shfl_xor(acc[d], 8);

  if (sub == 0){
    float inv = (c > 0) ? 1.f / dsum : 0.f;
    u16 o[16];
#pragma unroll
    for (int d = 0; d < 16; d++){
      float x = acc[d] * inv;
      o[d] = f2bf(0.5f * x * (1.f + erff(x * 0.70710678118654752f)));
    }
    uint4 p0, p1;
    p0.x = o[0]|(o[1]<<16);   p0.y = o[2]|(o[3]<<16);
    p0.z = o[4]|(o[5]<<16);   p0.w = o[6]|(o[7]<<16);
    p1.x = o[8]|(o[9]<<16);   p1.y = o[10]|(o[11]<<16);
    p1.z = o[12]|(o[13]<<16); p1.w = o[14]|(o[15]<<16);
    int b0 = slot*256 + h*32;
    int sw = (slot & 7) << 4;
    *(uint4*)((char*)G + (b0 ^ sw))        = p0;
    *(uint4*)((char*)G + ((b0 + 16) ^ sw)) = p1;
  }
  __syncthreads();   // G visible

  // ---- out-GEMM phase: 16x128 tile, wave w -> cols [w*32, w*32+32) ----
  short8 af[4];
  {
    int base = lm*256 + quad*16;
    int sw = (lm & 7) << 4;
#pragma unroll
    for (int c2 = 0; c2 < 4; c2++)
      af[c2] = *(const short8*)((const char*)G + ((base + c2*64) ^ sw));
  }
  f32x4 oacc[2];
#pragma unroll
  for (int nt = 0; nt < 2; nt++){
    oacc[nt] = (f32x4){0.f,0.f,0.f,0.f};
#pragma unroll
    for (int c2 = 0; c2 < 4; c2++)
      oacc[nt] = __builtin_amdgcn_mfma_f32_16x16x32_bf16(af[c2], wf[nt][c2], oacc[nt], 0, 0, 0);
  }
  float a_s = 1.f / (1.f + expf(-skipl[t]));
  float b_s = 1.f - a_s;
  const float* bias = bl + (size_t)t*128;
  float* X = Xall + (size_t)roff*128;
  u16* Xb = Xbfall ? (Xbfall + (size_t)roff*128) : (u16*)0;
#pragma unroll
  for (int nt = 0; nt < 2; nt++){
    int col = w*32 + nt*16 + lm;
    float bb = bias[col];
#pragma unroll
    for (int i = 0; i < 4; i++){
      int r = bm + quad*4 + i;
      float* xp = X + (size_t)r*128 + col;
      float x = *xp;
      float o = oacc[nt][i] + bb;
      float xn = fmaxf(a_s*o + b_s*x, 0.f) + x;
      *xp = xn;
      if (Xb) Xb[(size_t)r*128 + col] = f2bf(xn);
    }
  }
}

// ---------------- host ----------------

extern "C" void kernel_launch(void* const* d_in, const int* in_sizes, int n_in,
                              void* d_out, int out_size, void* d_ws, size_t ws_size,
                              hipStream_t stream)
{
  const float* xg   = (const float*)d_in[0];
  const float* xd   = (const float*)d_in[1];
  const float* xr_  = (const float*)d_in[2];
  const float* Wkqv = (const float*)d_in[3];
  const float* bkqv = (const float*)d_in[4];
  const float* Ak   = (const float*)d_in[5];
  const float* Av   = (const float*)d_in[6];
  const float* prel = (const float*)d_in[7];
  const float* Wout = (const float*)d_in[8];
  const float* bout = (const float*)d_in[9];
  const float* skip = (const float*)d_in[10];
  const int* ei[4] = {(const int*)d_in[11], (const int*)d_in[12],
                      (const int*)d_in[13], (const int*)d_in[14]};

  float* X = (float*)d_out;

  char* p = (char*)d_ws;
  auto alloc = [&](size_t b)->void*{ void* r = (void*)p; p += (b + 255) & ~(size_t)255; return r; };
  int*   cnt   = (int*)  alloc((size_t)NTOT * 4);
  int*   elist = (int*)  alloc((size_t)NTOT * SLOTS * 4);  // 41 MB padded
  float* beff  = (float*)alloc((size_t)8 * 256 * 4);
  u16*   qg    = (u16*)  alloc((size_t)NTOT * 128 * 2);    // 20.5 MB bf16
  u16*   kv    = (u16*)  alloc((size_t)NSRC * 256 * 2);    // 61.4 MB bf16
  u16*   Xbf   = (u16*)  alloc((size_t)NTOT * 128 * 2);    // 20.5 MB bf16
  u16*   WqT   = (u16*)  alloc((size_t)6 * 16384 * 2);
  u16*   WeffT = (u16*)  alloc((size_t)8 * 32768 * 2);
  u16*   WoutT = (u16*)  alloc((size_t)6 * 16384 * 2);
  (void)ws_size; (void)in_sizes; (void)n_in; (void)out_size;

  hipMemsetAsync(cnt, 0, (size_t)NTOT * 4, stream);

  prep_all<<<(PR4 + 255)/256, 256, 0, stream>>>(
      xg, xd, xr_, X, Xbf,
      Wkqv, bkqv, Ak, Av, Wout, WeffT, WqT, WoutT, beff,
      ei[0], ei[1], ei[2], ei[3], cnt, elist);

  for (int l = 0; l < 2; l++){
    mfma_gemm_qkv<<<1252, 256, 0, stream>>>(
        Xbf,
        WqT + (size_t)l*3*16384, bkqv + (size_t)l*3*384,
        WeffT + (size_t)l*4*32768, beff + (size_t)l*4*256,
        qg, kv);
    attn_out<<<5000, 256, 0, stream>>>(
        qg, kv, prel + l*32, cnt, elist,
        WoutT + (size_t)l*3*16384, bout + (size_t)l*3*128, skip + l*3,
        X, (l == 0) ? Xbf : (u16*)0);
  }
}